// Round 3
// baseline (375.039 us; speedup 1.0000x reference)
//
#include <hip/hip_runtime.h>
#include <hip/hip_bf16.h>
#include <math.h>

#define BB 4
#define LL 4096
#define DM 256
#define DI 512
#define DS 16
#define NOUTK 128
#define LN_EPS 1e-5f
#define NC 128
#define CLEN (LL/NC)
#define BL (BB*LL)
#define LDB 640

typedef __attribute__((ext_vector_type(8))) short short8;
typedef __attribute__((ext_vector_type(4))) float f32x4;

__device__ __forceinline__ ushort f2bf(float f) {
    union { float f; unsigned u; } v; v.f = f;
    unsigned r = (v.u + 0x7FFF + ((v.u >> 16) & 1)) >> 16;
    return (ushort)r;
}
__device__ __forceinline__ float bf2f(ushort u) {
    union { unsigned u; float f; } v; v.u = ((unsigned)u) << 16;
    return v.f;
}

// ---------------- weight prep ----------------------------------------------
__global__ __launch_bounds__(256) void cast_bf16_kernel(
    const float* __restrict__ src, ushort* __restrict__ dst, int n)
{
    int i = blockIdx.x * 256 + threadIdx.x;
    if (i < n) dst[i] = f2bf(src[i]);
}

// combined xproj weight: rows [0,512) = dtw @ xpw[:16]  (fused dtproj)
//                        rows [512,544) = xpw rows 16..47 (B, C)
//                        rows [544,640) = 0
__global__ __launch_bounds__(256) void build_comb_kernel(
    const float* __restrict__ xpw, const float* __restrict__ dtw,
    ushort* __restrict__ dst)
{
    int i = blockIdx.x * 256 + threadIdx.x;      // over 2*640*512
    int l = i / (640 * 512);
    int rem = i - l * 640 * 512;
    int row = rem >> 9, k = rem & 511;
    const float* xp = xpw + l * 48 * 512;
    const float* dw = dtw + l * 512 * 16;
    float v;
    if (row < 512) {
        v = 0.f;
        #pragma unroll
        for (int r = 0; r < 16; ++r)
            v = fmaf(dw[row * 16 + r], xp[r * 512 + k], v);
    } else if (row < 544) {
        v = xp[(row - 512 + 16) * 512 + k];
    } else v = 0.f;
    dst[i] = f2bf(v);
}

// ---------------- encoder --------------------------------------------------
__global__ __launch_bounds__(256) void enc_kernel(
    const float* __restrict__ x, const float* __restrict__ w,
    const float* __restrict__ b, float* __restrict__ h,
    ushort* __restrict__ hbf)
{
    __shared__ float sw[256 * 33];
    __shared__ float sx[4][32];
    int tid = threadIdx.x;
    for (int i = tid; i < 256 * 8; i += 256) {
        float4 v = ((const float4*)w)[i];
        int r = i >> 3, c = (i & 7) * 4;
        sw[r * 33 + c + 0] = v.x; sw[r * 33 + c + 1] = v.y;
        sw[r * 33 + c + 2] = v.z; sw[r * 33 + c + 3] = v.w;
    }
    int row0 = blockIdx.x * 4;
    if (tid < 32) {
        for (int rr = 0; rr < 4; ++rr)
            sx[rr][tid] = x[(size_t)(row0 + rr) * 32 + tid];
    }
    __syncthreads();
    float bb = b[tid];
    #pragma unroll
    for (int rr = 0; rr < 4; ++rr) {
        float acc = bb;
        #pragma unroll
        for (int k = 0; k < 32; ++k)
            acc = fmaf(sx[rr][k], sw[tid * 33 + k], acc);
        size_t o = (size_t)(row0 + rr) * DM + tid;
        h[o] = acc;
        hbf[o] = f2bf(acc);
    }
}

// ---------------- bf16 MFMA GEMM: C = epi(A @ W^T) -------------------------
// Tile 64(M) x 128(N), 4 waves of 32x64. Double-buffered LDS with
// RAW s_barrier + counted vmcnt(6): prefetch of tile t+1 stays in flight
// through compute of tile t (no vmcnt(0) drain in the main loop).
// EPI: 0 none; 1 combined-xproj:
//        cols<512:   dt_bf[row*ldcbf+col]  = bf16(softplus(v + bias[col]))
//        512<=c<544: bc  [row*ldc + c-512] = v   (f32 B/C block)
template<int EPI, bool F32OUT, bool RESID, bool BF16OUT>
__global__ __launch_bounds__(256, 4) void mfma_gemm(
    const ushort* __restrict__ A, int lda,
    const ushort* __restrict__ W,
    const float* __restrict__ bias,
    float* __restrict__ C, int ldc,
    ushort* __restrict__ Cbf, int ldcbf,
    int K)
{
    __shared__ __align__(16) ushort As[2][64 * 64];
    __shared__ __align__(16) ushort Ws[2][128 * 64];
    const int tid = threadIdx.x;

    // XCD-aware bijective swizzle (nwg % 8 == 0 for all our launches)
    int nwg = gridDim.x * gridDim.y;
    int wlin = blockIdx.y * gridDim.x + blockIdx.x;
    int gx = blockIdx.x, gy = blockIdx.y;
    if ((nwg & 7) == 0) {
        int q = nwg >> 3;
        int s = (wlin & 7) * q + (wlin >> 3);
        gx = s % gridDim.x;
        gy = s / gridDim.x;
    }
    const int bm = gy * 64;
    const int bn = gx * 128;
    const int wid = tid >> 6, lane = tid & 63;
    const int wrow = (wid >> 1) * 32, wcol = (wid & 1) * 64;
    const int sr = tid >> 3;
    const int sc = tid & 7;

    f32x4 acc[2][4];
    #pragma unroll
    for (int mi = 0; mi < 2; ++mi)
        #pragma unroll
        for (int ni = 0; ni < 4; ++ni)
            acc[mi][ni] = (f32x4){0.f, 0.f, 0.f, 0.f};

#define STAGE(buf, k0) do {                                                   \
    _Pragma("unroll")                                                         \
    for (int it = 0; it < 2; ++it) {                                          \
        int r = it * 32 + sr;                                                 \
        int csrc = sc ^ (r & 7);                                              \
        __builtin_amdgcn_global_load_lds(                                     \
            (const __attribute__((address_space(1))) unsigned int*)           \
                (A + (size_t)(bm + r) * lda + (k0) + csrc * 8),               \
            (__attribute__((address_space(3))) unsigned int*)                 \
                (&As[buf][r * 64 + sc * 8]), 16, 0, 0);                       \
    }                                                                         \
    _Pragma("unroll")                                                         \
    for (int it = 0; it < 4; ++it) {                                          \
        int r = it * 32 + sr;                                                 \
        int csrc = sc ^ (r & 7);                                              \
        __builtin_amdgcn_global_load_lds(                                     \
            (const __attribute__((address_space(1))) unsigned int*)           \
                (W + (size_t)(bn + r) * K + (k0) + csrc * 8),                 \
            (__attribute__((address_space(3))) unsigned int*)                 \
                (&Ws[buf][r * 64 + sc * 8]), 16, 0, 0);                       \
    }                                                                         \
} while (0)

#define COMPUTE(buf) do {                                                     \
    _Pragma("unroll")                                                         \
    for (int kk = 0; kk < 2; ++kk) {                                          \
        short8 af[2], bfr[4];                                                 \
        _Pragma("unroll")                                                     \
        for (int mi = 0; mi < 2; ++mi) {                                      \
            int r = wrow + mi * 16 + (lane & 15);                             \
            int c = (lane >> 4) + kk * 4;                                     \
            af[mi] = *(const short8*)(&As[buf][r * 64 + ((c ^ (r & 7)) << 3)]);\
        }                                                                     \
        _Pragma("unroll")                                                     \
        for (int ni = 0; ni < 4; ++ni) {                                      \
            int r = wcol + ni * 16 + (lane & 15);                             \
            int c = (lane >> 4) + kk * 4;                                     \
            bfr[ni] = *(const short8*)(&Ws[buf][r * 64 + ((c ^ (r & 7)) << 3)]);\
        }                                                                     \
        _Pragma("unroll")                                                     \
        for (int mi = 0; mi < 2; ++mi)                                        \
            _Pragma("unroll")                                                 \
            for (int ni = 0; ni < 4; ++ni)                                    \
                acc[mi][ni] = __builtin_amdgcn_mfma_f32_16x16x32_bf16(        \
                    af[mi], bfr[ni], acc[mi][ni], 0, 0, 0);                   \
    }                                                                         \
} while (0)

    const int nk = K >> 6;          // 4 (K=256) or 8 (K=512)
    STAGE(0, 0);
    for (int t = 0; t < nk; ++t) {
        if (t + 1 < nk) {
            STAGE((t + 1) & 1, (t + 1) << 6);
            // my 6 loads for tile t are complete; 6 newer stay in flight
            asm volatile("s_waitcnt vmcnt(6)" ::: "memory");
        } else {
            asm volatile("s_waitcnt vmcnt(0)" ::: "memory");
        }
        __builtin_amdgcn_s_barrier();        // everyone's tile-t loads done
        asm volatile("" ::: "memory");
        COMPUTE(t & 1);
        asm volatile("" ::: "memory");
        __builtin_amdgcn_s_barrier();        // all reads of buf t&1 done
    }
#undef STAGE
#undef COMPUTE

    #pragma unroll
    for (int mi = 0; mi < 2; ++mi)
        #pragma unroll
        for (int ni = 0; ni < 4; ++ni) {
            int col = bn + wcol + ni * 16 + (lane & 15);
            #pragma unroll
            for (int r = 0; r < 4; ++r) {
                int row = bm + wrow + mi * 16 + (lane >> 4) * 4 + r;
                float v = acc[mi][ni][r];
                if (EPI == 1) {
                    if (col < 512) {
                        float u = v + bias[col];
                        float sp = fmaxf(u, 0.f) + __logf(1.f + __expf(-fabsf(u)));
                        Cbf[(size_t)row * ldcbf + col] = f2bf(sp);
                    } else if (col < 544) {
                        C[(size_t)row * ldc + (col - 512)] = v;
                    }
                } else {
                    if (F32OUT) {
                        float* cp = C + (size_t)row * ldc + col;
                        float vv = v;
                        if (RESID) vv += *cp;
                        *cp = vv;
                        if (BF16OUT) Cbf[(size_t)row * ldcbf + col] = f2bf(vv);
                    } else if (BF16OUT) {
                        Cbf[(size_t)row * ldcbf + col] = f2bf(v);
                    }
                }
            }
        }
}

// ---------------- causal conv (width 4) + bias + silu, bf16 in/out ---------
__global__ __launch_bounds__(256) void conv_silu_kernel(
    const ushort* __restrict__ xz, const float* __restrict__ cw,
    const float* __restrict__ cb, ushort* __restrict__ xi)
{
    int idx = blockIdx.x * 256 + threadIdx.x;   // over BL*128
    int d4 = (idx & 127) * 4;
    int bt = idx >> 7;
    int t = bt & (LL - 1);
    const ushort* base = xz + (size_t)bt * 1024 + d4;
    float acc[4];
    float4 w[4];
    #pragma unroll
    for (int j = 0; j < 4; ++j) {
        acc[j] = cb[d4 + j];
        w[j] = *(const float4*)(cw + (d4 + j) * 4);
    }
    #pragma unroll
    for (int k = 0; k < 4; ++k) {
        int back = 3 - k;
        if (t >= back) {
            ushort4 v = *(const ushort4*)(base - back * 1024);
            float wk0 = (k==0)?w[0].x:(k==1)?w[0].y:(k==2)?w[0].z:w[0].w;
            float wk1 = (k==0)?w[1].x:(k==1)?w[1].y:(k==2)?w[1].z:w[1].w;
            float wk2 = (k==0)?w[2].x:(k==1)?w[2].y:(k==2)?w[2].z:w[2].w;
            float wk3 = (k==0)?w[3].x:(k==1)?w[3].y:(k==2)?w[3].z:w[3].w;
            acc[0] = fmaf(bf2f(v.x), wk0, acc[0]);
            acc[1] = fmaf(bf2f(v.y), wk1, acc[1]);
            acc[2] = fmaf(bf2f(v.z), wk2, acc[2]);
            acc[3] = fmaf(bf2f(v.w), wk3, acc[3]);
        }
    }
    ushort4 o;
    float s0 = acc[0] / (1.f + __expf(-acc[0]));
    float s1 = acc[1] / (1.f + __expf(-acc[1]));
    float s2 = acc[2] / (1.f + __expf(-acc[2]));
    float s3 = acc[3] / (1.f + __expf(-acc[3]));
    o.x = f2bf(s0); o.y = f2bf(s1); o.z = f2bf(s2); o.w = f2bf(s3);
    *(ushort4*)(xi + (size_t)bt * 512 + d4) = o;
}

// ---------------- chunked selective scan -----------------------------------
// dt (softplus applied) is bf16 at dtb[row*512 + d]; B/C are f32 at
// bc[row*32 + {0..15 | 16..31}].
__global__ __launch_bounds__(256) void scan_phase1(
    const ushort* __restrict__ xi, const ushort* __restrict__ dtb,
    const float* __restrict__ bc,
    const float* __restrict__ alog,
    float* __restrict__ cA, float* __restrict__ cH)
{
    int d = blockIdx.z * 256 + threadIdx.x;
    int b = blockIdx.y, c = blockIdx.x;
    float Av[16];
    bool fast = true;
    #pragma unroll
    for (int s = 0; s < 16; ++s) {
        Av[s] = -__expf(alog[d * 16 + s]);
        fast = fast && (fabsf(Av[s] + (float)(s + 1)) < 1e-3f * (s + 1));
    }
    float h[16], P[16];
    #pragma unroll
    for (int s = 0; s < 16; ++s) { h[s] = 0.f; P[s] = 1.f; }
    int t0 = c * CLEN;
    if (fast) {
        float Pe = 1.f;
        for (int t = t0; t < t0 + CLEN; ++t) {
            size_t row = (size_t)b * LL + t;
            float dt = bf2f(dtb[row * 512 + d]);
            float x = bf2f(xi[row * 512 + d]);
            float dtx = dt * x;
            const float* bp = bc + row * 32;
            float e1 = __expf(-dt);
            float e2=e1*e1, e3=e2*e1, e4=e2*e2, e5=e3*e2, e6=e3*e3, e7=e4*e3, e8=e4*e4;
            float e9=e5*e4, e10=e5*e5, e11=e6*e5, e12=e6*e6, e13=e7*e6, e14=e7*e7, e15=e8*e7, e16=e8*e8;
            float pw[16] = {e1,e2,e3,e4,e5,e6,e7,e8,e9,e10,e11,e12,e13,e14,e15,e16};
            #pragma unroll
            for (int s = 0; s < 16; ++s)
                h[s] = fmaf(pw[s], h[s], dtx * bp[s]);
            Pe *= e1;
        }
        float p1=Pe, p2=p1*p1, p3=p2*p1, p4=p2*p2, p5=p3*p2, p6=p3*p3, p7=p4*p3, p8=p4*p4;
        float p9=p5*p4, p10=p5*p5, p11=p6*p5, p12=p6*p6, p13=p7*p6, p14=p7*p7, p15=p8*p7, p16=p8*p8;
        float pp[16] = {p1,p2,p3,p4,p5,p6,p7,p8,p9,p10,p11,p12,p13,p14,p15,p16};
        #pragma unroll
        for (int s = 0; s < 16; ++s) P[s] = pp[s];
    } else {
        for (int t = t0; t < t0 + CLEN; ++t) {
            size_t row = (size_t)b * LL + t;
            float dt = bf2f(dtb[row * 512 + d]);
            float x = bf2f(xi[row * 512 + d]);
            float dtx = dt * x;
            const float* bp = bc + row * 32;
            #pragma unroll
            for (int s = 0; s < 16; ++s) {
                float dA = __expf(dt * Av[s]);
                h[s] = fmaf(dA, h[s], dtx * bp[s]);
                P[s] *= dA;
            }
        }
    }
    size_t base = (((size_t)b * DI + d) * NC + c) * 16;
    #pragma unroll
    for (int q = 0; q < 4; ++q) {
        *(float4*)(cA + base + q*4) = *(float4*)&P[q*4];
        *(float4*)(cH + base + q*4) = *(float4*)&h[q*4];
    }
}

// Parallel chunk-prefix: one block per (b,d); 16 threads per s-value,
// each composing 8 chunks; shfl-scan of affine maps F(x)=Ax+H across the
// 16-lane segment (serial chain 128 -> 8+4+8).
__global__ __launch_bounds__(256) void scan_phase2(
    const float* __restrict__ cA, float* __restrict__ cH)
{
    int bd = blockIdx.x;            // 0 .. BB*DI-1
    int tid = threadIdx.x;
    int s = tid >> 4;               // 0..15
    int g = tid & 15;               // chunk group (8 chunks each)
    size_t base = (size_t)bd * NC * 16 + s;
    float a8[8], h8[8];
    #pragma unroll
    for (int j = 0; j < 8; ++j) {
        size_t o = base + (size_t)(g * 8 + j) * 16;
        a8[j] = cA[o]; h8[j] = cH[o];
    }
    float A = 1.f, H = 0.f;
    #pragma unroll
    for (int j = 0; j < 8; ++j) {
        H = fmaf(a8[j], H, h8[j]);
        A *= a8[j];
    }
    // inclusive scan over 16-lane segments; combine(prev_earlier, cur):
    // A = Acur*Aprev, H = Acur*Hprev + Hcur
    #pragma unroll
    for (int off = 1; off < 16; off <<= 1) {
        float Ap = __shfl_up(A, off, 16);
        float Hp = __shfl_up(H, off, 16);
        if (g >= off) { H = fmaf(A, Hp, H); A *= Ap; }
    }
    // exclusive prefix state (initial state 0 => state = H_excl)
    float init = __shfl_up(H, 1, 16);
    if (g == 0) init = 0.f;
    #pragma unroll
    for (int j = 0; j < 8; ++j) {
        size_t o = base + (size_t)(g * 8 + j) * 16;
        cH[o] = init;
        init = fmaf(a8[j], init, h8[j]);
    }
}

__global__ __launch_bounds__(256) void scan_phase3(
    const ushort* __restrict__ xz,   // bf16, ld 1024; res at cols 512..1023
    ushort* __restrict__ xi,
    const ushort* __restrict__ dtb,
    const float* __restrict__ bc,
    const float* __restrict__ alog,
    const float* __restrict__ Dp,
    const float* __restrict__ cH,
    int c0)
{
    int d = blockIdx.z * 256 + threadIdx.x;
    int b = blockIdx.y;
    int c = blockIdx.x + c0;
    float Av[16];
    bool fast = true;
    #pragma unroll
    for (int s = 0; s < 16; ++s) {
        Av[s] = -__expf(alog[d * 16 + s]);
        fast = fast && (fabsf(Av[s] + (float)(s + 1)) < 1e-3f * (s + 1));
    }
    float h[16];
    size_t cbase = (((size_t)b * DI + d) * NC + c) * 16;
    #pragma unroll
    for (int q = 0; q < 4; ++q)
        *(float4*)&h[q*4] = *(const float4*)(cH + cbase + q*4);
    float Dd = Dp[d];
    int t0 = c * CLEN;
    if (fast) {
        for (int t = t0; t < t0 + CLEN; ++t) {
            size_t row = (size_t)b * LL + t;
            float dt = bf2f(dtb[row * 512 + d]);
            float x = bf2f(xi[row * 512 + d]);
            float dtx = dt * x;
            const float* bp = bc + row * 32;
            const float* cp = bc + row * 32 + 16;
            float e1 = __expf(-dt);
            float e2=e1*e1, e3=e2*e1, e4=e2*e2, e5=e3*e2, e6=e3*e3, e7=e4*e3, e8=e4*e4;
            float e9=e5*e4, e10=e5*e5, e11=e6*e5, e12=e6*e6, e13=e7*e6, e14=e7*e7, e15=e8*e7, e16=e8*e8;
            float pw[16] = {e1,e2,e3,e4,e5,e6,e7,e8,e9,e10,e11,e12,e13,e14,e15,e16};
            float y = 0.f;
            #pragma unroll
            for (int s = 0; s < 16; ++s) {
                h[s] = fmaf(pw[s], h[s], dtx * bp[s]);
                y = fmaf(h[s], cp[s], y);
            }
            float res = bf2f(xz[row * 1024 + 512 + d]);
            float g = (y + x * Dd) * (res / (1.f + __expf(-res)));
            xi[row * 512 + d] = f2bf(g);
        }
    } else {
        for (int t = t0; t < t0 + CLEN; ++t) {
            size_t row = (size_t)b * LL + t;
            float dt = bf2f(dtb[row * 512 + d]);
            float x = bf2f(xi[row * 512 + d]);
            float dtx = dt * x;
            const float* bp = bc + row * 32;
            const float* cp = bc + row * 32 + 16;
            float y = 0.f;
            #pragma unroll
            for (int s = 0; s < 16; ++s) {
                float dA = __expf(dt * Av[s]);
                h[s] = fmaf(dA, h[s], dtx * bp[s]);
                y = fmaf(h[s], cp[s], y);
            }
            float res = bf2f(xz[row * 1024 + 512 + d]);
            float g = (y + x * Dd) * (res / (1.f + __expf(-res)));
            xi[row * 512 + d] = f2bf(g);
        }
    }
}

// ---------------- last-row out_proj (layer 2) ------------------------------
__global__ __launch_bounds__(256) void out_proj_last_kernel(
    const ushort* __restrict__ xi, const float* __restrict__ W,
    float* __restrict__ h)
{
    int b = blockIdx.x, n = threadIdx.x;
    __shared__ float sy[DI];
    const ushort* yrow = xi + ((size_t)b * LL + (LL - 1)) * DI;
    for (int k = threadIdx.x; k < DI; k += 256) sy[k] = bf2f(yrow[k]);
    __syncthreads();
    const float* wr = W + (size_t)n * DI;
    float acc = 0.f;
    for (int k = 0; k < DI; k += 4) {
        float4 wv = *(const float4*)(wr + k);
        acc = fmaf(sy[k+0], wv.x, acc);
        acc = fmaf(sy[k+1], wv.y, acc);
        acc = fmaf(sy[k+2], wv.z, acc);
        acc = fmaf(sy[k+3], wv.w, acc);
    }
    h[((size_t)b * LL + (LL - 1)) * DM + n] += acc;
}

// ---------------- final LN (last row only) + head --------------------------
__global__ __launch_bounds__(256) void ln_head_kernel(
    const float* __restrict__ h, const float* __restrict__ lng,
    const float* __restrict__ lnb, const float* __restrict__ hw,
    const float* __restrict__ hb, float* __restrict__ out)
{
    int b = blockIdx.x, tid = threadIdx.x;
    __shared__ float sh[DM];
    __shared__ float r1[4], r2[4];
    float v = h[((size_t)b * LL + (LL - 1)) * DM + tid];
    float s = v;
    #pragma unroll
    for (int o = 32; o >= 1; o >>= 1) s += __shfl_down(s, o);
    if ((tid & 63) == 0) r1[tid >> 6] = s;
    __syncthreads();
    float mu = (r1[0] + r1[1] + r1[2] + r1[3]) * (1.f / 256.f);
    float dv = v - mu;
    float q = dv * dv;
    #pragma unroll
    for (int o = 32; o >= 1; o >>= 1) q += __shfl_down(q, o);
    if ((tid & 63) == 0) r2[tid >> 6] = q;
    __syncthreads();
    float var = (r2[0] + r2[1] + r2[2] + r2[3]) * (1.f / 256.f);
    sh[tid] = dv * rsqrtf(var + LN_EPS) * lng[tid] + lnb[tid];
    __syncthreads();
    if (tid < NOUTK) {
        const float* wr = hw + (size_t)tid * DM;
        float acc = hb[tid];
        for (int d2 = 0; d2 < DM; d2 += 4) {
            float4 wv = *(const float4*)(wr + d2);
            acc = fmaf(sh[d2+0], wv.x, acc);
            acc = fmaf(sh[d2+1], wv.y, acc);
            acc = fmaf(sh[d2+2], wv.z, acc);
            acc = fmaf(sh[d2+3], wv.w, acc);
        }
        out[b * NOUTK + tid] = acc;
    }
}

extern "C" void kernel_launch(void* const* d_in, const int* in_sizes, int n_in,
                              void* d_out, int out_size, void* d_ws, size_t ws_size,
                              hipStream_t stream)
{
    const float* x    = (const float*)d_in[0];
    const float* encw = (const float*)d_in[1];
    const float* encb = (const float*)d_in[2];
    const float* inw  = (const float*)d_in[3];
    const float* cw   = (const float*)d_in[4];
    const float* cb   = (const float*)d_in[5];
    const float* xpw  = (const float*)d_in[6];
    const float* dtw  = (const float*)d_in[7];
    const float* dtb  = (const float*)d_in[8];
    const float* alog = (const float*)d_in[9];
    const float* Dp   = (const float*)d_in[10];
    const float* opw  = (const float*)d_in[11];
    const float* lng  = (const float*)d_in[12];
    const float* lnb  = (const float*)d_in[13];
    const float* hw   = (const float*)d_in[14];
    const float* hb   = (const float*)d_in[15];
    float* out = (float*)d_out;

    float* ws   = (float*)d_ws;
    float* h    = ws;                               // BL*256 f32
    float* bc   = h   + (size_t)BL * DM;            // BL*32 f32 (B|C)
    float* cA   = bc  + (size_t)BL * 32;            // B*DI*NC*16 f32
    float* cH   = cA  + (size_t)BB * DI * NC * DS;
    ushort* h_bf    = (ushort*)(cH + (size_t)BB * DI * NC * DS);
    ushort* xz_bf   = h_bf  + (size_t)BL * DM;      // BL*1024
    ushort* xi_bf   = xz_bf + (size_t)BL * 1024;    // BL*512
    ushort* dt_bf   = xi_bf + (size_t)BL * DI;      // BL*512 (softplus'd dt)
    ushort* inw_bf  = dt_bf + (size_t)BL * DI;      // 2*1024*256
    ushort* opw_bf  = inw_bf + 2 * 1024 * DM;       // 2*256*512
    ushort* comb_bf = opw_bf + 2 * DM * DI;         // 2*640*512

    dim3 blk(256, 1, 1);

    cast_bf16_kernel<<<dim3((2*1024*DM)/256), blk, 0, stream>>>(inw, inw_bf, 2*1024*DM);
    cast_bf16_kernel<<<dim3((2*DM*DI)/256), blk, 0, stream>>>(opw, opw_bf, 2*DM*DI);
    build_comb_kernel<<<dim3((2*640*512)/256), blk, 0, stream>>>(xpw, dtw, comb_bf);

    enc_kernel<<<dim3(BL/4), blk, 0, stream>>>(x, encw, encb, h, h_bf);

    for (int l = 0; l < 2; ++l) {
        // in_proj -> xz_bf (bf16 only)
        mfma_gemm<0,false,false,true><<<dim3(1024/128, BL/64), blk, 0, stream>>>(
            h_bf, DM, inw_bf + (size_t)l * 1024 * DM, nullptr,
            nullptr, 0, xz_bf, 1024, DM);
        // conv + silu -> xi_bf
        conv_silu_kernel<<<dim3(BL * 128 / 256), blk, 0, stream>>>(
            xz_bf, cw + l * DI * 4, cb + l * DI, xi_bf);
        // combined xproj+dtproj: dt_bf = bf16(softplus(xi@Wdt^T + dtb)),
        // bc = f32 [B|C]
        mfma_gemm<1,false,false,false><<<dim3(LDB/128, BL/64), blk, 0, stream>>>(
            xi_bf, DI, comb_bf + (size_t)l * LDB * DI, dtb + l * DI,
            bc, 32, dt_bf, 512, DI);
        // scan
        scan_phase1<<<dim3(NC, BB, 2), blk, 0, stream>>>(
            xi_bf, dt_bf, bc, alog + (size_t)l * DI * 16, cA, cH);
        scan_phase2<<<dim3(BB * DI), blk, 0, stream>>>(cA, cH);
        if (l == 0) {
            scan_phase3<<<dim3(NC, BB, 2), blk, 0, stream>>>(
                xz_bf, xi_bf, dt_bf, bc, alog + (size_t)l * DI * 16,
                Dp + l * DI, cH, 0);
            mfma_gemm<0,true,true,true><<<dim3(DM/128, BL/64), blk, 0, stream>>>(
                xi_bf, DI, opw_bf + (size_t)l * DM * DI, nullptr,
                h, DM, h_bf, DM, DI);
        } else {
            scan_phase3<<<dim3(1, BB, 2), blk, 0, stream>>>(
                xz_bf, xi_bf, dt_bf, bc, alog + (size_t)l * DI * 16,
                Dp + l * DI, cH, NC - 1);
            out_proj_last_kernel<<<dim3(BB), blk, 0, stream>>>(
                xi_bf, opw + (size_t)l * DM * DI, h);
        }
    }

    ln_head_kernel<<<dim3(BB), blk, 0, stream>>>(h, lng, lnb, hw, hb, out);
}

// Round 4
// 369.719 us; speedup vs baseline: 1.0144x; 1.0144x over previous
//
#include <hip/hip_runtime.h>
#include <hip/hip_bf16.h>
#include <math.h>

#define BB 4
#define LL 4096
#define DM 256
#define DI 512
#define DS 16
#define NOUTK 128
#define LN_EPS 1e-5f
#define NC 128
#define CLEN (LL/NC)
#define BL (BB*LL)
#define LDB 640

typedef __attribute__((ext_vector_type(8))) short short8;
typedef __attribute__((ext_vector_type(4))) float f32x4;

__device__ __forceinline__ ushort f2bf(float f) {
    union { float f; unsigned u; } v; v.f = f;
    unsigned r = (v.u + 0x7FFF + ((v.u >> 16) & 1)) >> 16;
    return (ushort)r;
}
__device__ __forceinline__ float bf2f(ushort u) {
    union { unsigned u; float f; } v; v.u = ((unsigned)u) << 16;
    return v.f;
}

// ---------------- weight prep ----------------------------------------------
__global__ __launch_bounds__(256) void cast_bf16_kernel(
    const float* __restrict__ src, ushort* __restrict__ dst, int n)
{
    int i = blockIdx.x * 256 + threadIdx.x;
    if (i < n) dst[i] = f2bf(src[i]);
}

// combined xproj weight: rows [0,512) = dtw @ xpw[:16]  (fused dtproj)
//                        rows [512,544) = xpw rows 16..47 (B, C)
//                        rows [544,640) = 0
__global__ __launch_bounds__(256) void build_comb_kernel(
    const float* __restrict__ xpw, const float* __restrict__ dtw,
    ushort* __restrict__ dst)
{
    int i = blockIdx.x * 256 + threadIdx.x;      // over 2*640*512
    int l = i / (640 * 512);
    int rem = i - l * 640 * 512;
    int row = rem >> 9, k = rem & 511;
    const float* xp = xpw + l * 48 * 512;
    const float* dw = dtw + l * 512 * 16;
    float v;
    if (row < 512) {
        v = 0.f;
        #pragma unroll
        for (int r = 0; r < 16; ++r)
            v = fmaf(dw[row * 16 + r], xp[r * 512 + k], v);
    } else if (row < 544) {
        v = xp[(row - 512 + 16) * 512 + k];
    } else v = 0.f;
    dst[i] = f2bf(v);
}

// ---------------- encoder --------------------------------------------------
__global__ __launch_bounds__(256) void enc_kernel(
    const float* __restrict__ x, const float* __restrict__ w,
    const float* __restrict__ b, float* __restrict__ h,
    ushort* __restrict__ hbf)
{
    __shared__ float sw[256 * 33];
    __shared__ float sx[4][32];
    int tid = threadIdx.x;
    for (int i = tid; i < 256 * 8; i += 256) {
        float4 v = ((const float4*)w)[i];
        int r = i >> 3, c = (i & 7) * 4;
        sw[r * 33 + c + 0] = v.x; sw[r * 33 + c + 1] = v.y;
        sw[r * 33 + c + 2] = v.z; sw[r * 33 + c + 3] = v.w;
    }
    int row0 = blockIdx.x * 4;
    if (tid < 32) {
        for (int rr = 0; rr < 4; ++rr)
            sx[rr][tid] = x[(size_t)(row0 + rr) * 32 + tid];
    }
    __syncthreads();
    float bb = b[tid];
    #pragma unroll
    for (int rr = 0; rr < 4; ++rr) {
        float acc = bb;
        #pragma unroll
        for (int k = 0; k < 32; ++k)
            acc = fmaf(sx[rr][k], sw[tid * 33 + k], acc);
        size_t o = (size_t)(row0 + rr) * DM + tid;
        h[o] = acc;
        hbf[o] = f2bf(acc);
    }
}

// ---------------- bf16 MFMA GEMM: C = epi(A @ W^T) -------------------------
// Tile 64(M) x 128(N), 4 waves of 32x64, single-buffered 24 KB LDS
// (m97-style 2-barrier k-loop; latency hidden by 5-6 co-resident blocks).
// NOTE (R3 post-mortem): do NOT double-buffer this — 48 KB LDS halves
// co-resident blocks (6->3) and the lost TLP costs more than the explicit
// pipeline gains at K=256/512 (round 3: +31 us regression).
// EPI: 0 none; 1 combined-xproj:
//        cols<512:   dt_bf[row*ldcbf+col]  = bf16(softplus(v + bias[col]))
//        512<=c<544: bc  [row*ldc + c-512] = v   (f32 B/C block)
template<int EPI, bool F32OUT, bool RESID, bool BF16OUT>
__global__ __launch_bounds__(256, 4) void mfma_gemm(
    const ushort* __restrict__ A, int lda,
    const ushort* __restrict__ W,
    const float* __restrict__ bias,
    float* __restrict__ C, int ldc,
    ushort* __restrict__ Cbf, int ldcbf,
    int K)
{
    __shared__ ushort As[64 * 64];
    __shared__ ushort Ws[128 * 64];
    const int tid = threadIdx.x;

    // XCD-aware bijective swizzle (nwg % 8 == 0 for all our launches)
    int nwg = gridDim.x * gridDim.y;
    int wlin = blockIdx.y * gridDim.x + blockIdx.x;
    int gx = blockIdx.x, gy = blockIdx.y;
    if ((nwg & 7) == 0) {
        int q = nwg >> 3;
        int s = (wlin & 7) * q + (wlin >> 3);
        gx = s % gridDim.x;
        gy = s / gridDim.x;
    }
    const int bm = gy * 64;
    const int bn = gx * 128;
    const int wid = tid >> 6, lane = tid & 63;
    const int wrow = (wid >> 1) * 32, wcol = (wid & 1) * 64;
    const int sr = tid >> 3;
    const int sc = tid & 7;

    f32x4 acc[2][4];
    #pragma unroll
    for (int mi = 0; mi < 2; ++mi)
        #pragma unroll
        for (int ni = 0; ni < 4; ++ni)
            acc[mi][ni] = (f32x4){0.f, 0.f, 0.f, 0.f};

    const int nk = K >> 6;          // 4 (K=256) or 8 (K=512)
    for (int t = 0; t < nk; ++t) {
        const int k0 = t << 6;
        #pragma unroll
        for (int it = 0; it < 2; ++it) {
            int r = it * 32 + sr;
            int csrc = sc ^ (r & 7);
            __builtin_amdgcn_global_load_lds(
                (const __attribute__((address_space(1))) unsigned int*)
                    (A + (size_t)(bm + r) * lda + k0 + csrc * 8),
                (__attribute__((address_space(3))) unsigned int*)
                    (As + r * 64 + sc * 8), 16, 0, 0);
        }
        #pragma unroll
        for (int it = 0; it < 4; ++it) {
            int r = it * 32 + sr;
            int csrc = sc ^ (r & 7);
            __builtin_amdgcn_global_load_lds(
                (const __attribute__((address_space(1))) unsigned int*)
                    (W + (size_t)(bn + r) * K + k0 + csrc * 8),
                (__attribute__((address_space(3))) unsigned int*)
                    (Ws + r * 64 + sc * 8), 16, 0, 0);
        }
        __syncthreads();
        #pragma unroll
        for (int kk = 0; kk < 2; ++kk) {
            short8 af[2], bfr[4];
            #pragma unroll
            for (int mi = 0; mi < 2; ++mi) {
                int r = wrow + mi * 16 + (lane & 15);
                int c = (lane >> 4) + kk * 4;
                af[mi] = *(const short8*)(As + r * 64 + ((c ^ (r & 7)) << 3));
            }
            #pragma unroll
            for (int ni = 0; ni < 4; ++ni) {
                int r = wcol + ni * 16 + (lane & 15);
                int c = (lane >> 4) + kk * 4;
                bfr[ni] = *(const short8*)(Ws + r * 64 + ((c ^ (r & 7)) << 3));
            }
            #pragma unroll
            for (int mi = 0; mi < 2; ++mi)
                #pragma unroll
                for (int ni = 0; ni < 4; ++ni)
                    acc[mi][ni] = __builtin_amdgcn_mfma_f32_16x16x32_bf16(
                        af[mi], bfr[ni], acc[mi][ni], 0, 0, 0);
        }
        __syncthreads();
    }

    #pragma unroll
    for (int mi = 0; mi < 2; ++mi)
        #pragma unroll
        for (int ni = 0; ni < 4; ++ni) {
            int col = bn + wcol + ni * 16 + (lane & 15);
            #pragma unroll
            for (int r = 0; r < 4; ++r) {
                int row = bm + wrow + mi * 16 + (lane >> 4) * 4 + r;
                float v = acc[mi][ni][r];
                if (EPI == 1) {
                    if (col < 512) {
                        float u = v + bias[col];
                        float sp = fmaxf(u, 0.f) + __logf(1.f + __expf(-fabsf(u)));
                        Cbf[(size_t)row * ldcbf + col] = f2bf(sp);
                    } else if (col < 544) {
                        C[(size_t)row * ldc + (col - 512)] = v;
                    }
                } else {
                    if (F32OUT) {
                        float* cp = C + (size_t)row * ldc + col;
                        float vv = v;
                        if (RESID) vv += *cp;
                        *cp = vv;
                        if (BF16OUT) Cbf[(size_t)row * ldcbf + col] = f2bf(vv);
                    } else if (BF16OUT) {
                        Cbf[(size_t)row * ldcbf + col] = f2bf(v);
                    }
                }
            }
        }
}

// ---------------- causal conv (width 4) + bias + silu, bf16 in/out ---------
__global__ __launch_bounds__(256) void conv_silu_kernel(
    const ushort* __restrict__ xz, const float* __restrict__ cw,
    const float* __restrict__ cb, ushort* __restrict__ xi)
{
    int idx = blockIdx.x * 256 + threadIdx.x;   // over BL*128
    int d4 = (idx & 127) * 4;
    int bt = idx >> 7;
    int t = bt & (LL - 1);
    const ushort* base = xz + (size_t)bt * 1024 + d4;
    float acc[4];
    float4 w[4];
    #pragma unroll
    for (int j = 0; j < 4; ++j) {
        acc[j] = cb[d4 + j];
        w[j] = *(const float4*)(cw + (d4 + j) * 4);
    }
    #pragma unroll
    for (int k = 0; k < 4; ++k) {
        int back = 3 - k;
        if (t >= back) {
            ushort4 v = *(const ushort4*)(base - back * 1024);
            float wk0 = (k==0)?w[0].x:(k==1)?w[0].y:(k==2)?w[0].z:w[0].w;
            float wk1 = (k==0)?w[1].x:(k==1)?w[1].y:(k==2)?w[1].z:w[1].w;
            float wk2 = (k==0)?w[2].x:(k==1)?w[2].y:(k==2)?w[2].z:w[2].w;
            float wk3 = (k==0)?w[3].x:(k==1)?w[3].y:(k==2)?w[3].z:w[3].w;
            acc[0] = fmaf(bf2f(v.x), wk0, acc[0]);
            acc[1] = fmaf(bf2f(v.y), wk1, acc[1]);
            acc[2] = fmaf(bf2f(v.z), wk2, acc[2]);
            acc[3] = fmaf(bf2f(v.w), wk3, acc[3]);
        }
    }
    ushort4 o;
    float s0 = acc[0] / (1.f + __expf(-acc[0]));
    float s1 = acc[1] / (1.f + __expf(-acc[1]));
    float s2 = acc[2] / (1.f + __expf(-acc[2]));
    float s3 = acc[3] / (1.f + __expf(-acc[3]));
    o.x = f2bf(s0); o.y = f2bf(s1); o.z = f2bf(s2); o.w = f2bf(s3);
    *(ushort4*)(xi + (size_t)bt * 512 + d4) = o;
}

// ---------------- chunked selective scan -----------------------------------
// dt (softplus applied) is bf16 at dtb[row*512 + d]; B/C are f32 at
// bc[row*32 + {0..15 | 16..31}].
__global__ __launch_bounds__(256) void scan_phase1(
    const ushort* __restrict__ xi, const ushort* __restrict__ dtb,
    const float* __restrict__ bc,
    const float* __restrict__ alog,
    float* __restrict__ cA, float* __restrict__ cH)
{
    int d = blockIdx.z * 256 + threadIdx.x;
    int b = blockIdx.y, c = blockIdx.x;
    float Av[16];
    bool fast = true;
    #pragma unroll
    for (int s = 0; s < 16; ++s) {
        Av[s] = -__expf(alog[d * 16 + s]);
        fast = fast && (fabsf(Av[s] + (float)(s + 1)) < 1e-3f * (s + 1));
    }
    float h[16], P[16];
    #pragma unroll
    for (int s = 0; s < 16; ++s) { h[s] = 0.f; P[s] = 1.f; }
    int t0 = c * CLEN;
    if (fast) {
        float Pe = 1.f;
        for (int t = t0; t < t0 + CLEN; ++t) {
            size_t row = (size_t)b * LL + t;
            float dt = bf2f(dtb[row * 512 + d]);
            float x = bf2f(xi[row * 512 + d]);
            float dtx = dt * x;
            const float* bp = bc + row * 32;
            float e1 = __expf(-dt);
            float e2=e1*e1, e3=e2*e1, e4=e2*e2, e5=e3*e2, e6=e3*e3, e7=e4*e3, e8=e4*e4;
            float e9=e5*e4, e10=e5*e5, e11=e6*e5, e12=e6*e6, e13=e7*e6, e14=e7*e7, e15=e8*e7, e16=e8*e8;
            float pw[16] = {e1,e2,e3,e4,e5,e6,e7,e8,e9,e10,e11,e12,e13,e14,e15,e16};
            #pragma unroll
            for (int s = 0; s < 16; ++s)
                h[s] = fmaf(pw[s], h[s], dtx * bp[s]);
            Pe *= e1;
        }
        float p1=Pe, p2=p1*p1, p3=p2*p1, p4=p2*p2, p5=p3*p2, p6=p3*p3, p7=p4*p3, p8=p4*p4;
        float p9=p5*p4, p10=p5*p5, p11=p6*p5, p12=p6*p6, p13=p7*p6, p14=p7*p7, p15=p8*p7, p16=p8*p8;
        float pp[16] = {p1,p2,p3,p4,p5,p6,p7,p8,p9,p10,p11,p12,p13,p14,p15,p16};
        #pragma unroll
        for (int s = 0; s < 16; ++s) P[s] = pp[s];
    } else {
        for (int t = t0; t < t0 + CLEN; ++t) {
            size_t row = (size_t)b * LL + t;
            float dt = bf2f(dtb[row * 512 + d]);
            float x = bf2f(xi[row * 512 + d]);
            float dtx = dt * x;
            const float* bp = bc + row * 32;
            #pragma unroll
            for (int s = 0; s < 16; ++s) {
                float dA = __expf(dt * Av[s]);
                h[s] = fmaf(dA, h[s], dtx * bp[s]);
                P[s] *= dA;
            }
        }
    }
    size_t base = (((size_t)b * DI + d) * NC + c) * 16;
    #pragma unroll
    for (int q = 0; q < 4; ++q) {
        *(float4*)(cA + base + q*4) = *(float4*)&P[q*4];
        *(float4*)(cH + base + q*4) = *(float4*)&h[q*4];
    }
}

// Parallel chunk-prefix: one block per (b,d); 16 threads per s-value,
// each composing 8 chunks; shfl-scan of affine maps F(x)=Ax+H across the
// 16-lane segment (serial chain 128 -> 8+4+8).
__global__ __launch_bounds__(256) void scan_phase2(
    const float* __restrict__ cA, float* __restrict__ cH)
{
    int bd = blockIdx.x;            // 0 .. BB*DI-1
    int tid = threadIdx.x;
    int s = tid >> 4;               // 0..15
    int g = tid & 15;               // chunk group (8 chunks each)
    size_t base = (size_t)bd * NC * 16 + s;
    float a8[8], h8[8];
    #pragma unroll
    for (int j = 0; j < 8; ++j) {
        size_t o = base + (size_t)(g * 8 + j) * 16;
        a8[j] = cA[o]; h8[j] = cH[o];
    }
    float A = 1.f, H = 0.f;
    #pragma unroll
    for (int j = 0; j < 8; ++j) {
        H = fmaf(a8[j], H, h8[j]);
        A *= a8[j];
    }
    // inclusive scan over 16-lane segments; combine(prev_earlier, cur):
    // A = Acur*Aprev, H = Acur*Hprev + Hcur
    #pragma unroll
    for (int off = 1; off < 16; off <<= 1) {
        float Ap = __shfl_up(A, off, 16);
        float Hp = __shfl_up(H, off, 16);
        if (g >= off) { H = fmaf(A, Hp, H); A *= Ap; }
    }
    // exclusive prefix state (initial state 0 => state = H_excl)
    float init = __shfl_up(H, 1, 16);
    if (g == 0) init = 0.f;
    #pragma unroll
    for (int j = 0; j < 8; ++j) {
        size_t o = base + (size_t)(g * 8 + j) * 16;
        cH[o] = init;
        init = fmaf(a8[j], init, h8[j]);
    }
}

__global__ __launch_bounds__(256) void scan_phase3(
    const ushort* __restrict__ xz,   // bf16, ld 1024; res at cols 512..1023
    ushort* __restrict__ xi,
    const ushort* __restrict__ dtb,
    const float* __restrict__ bc,
    const float* __restrict__ alog,
    const float* __restrict__ Dp,
    const float* __restrict__ cH,
    int c0)
{
    int d = blockIdx.z * 256 + threadIdx.x;
    int b = blockIdx.y;
    int c = blockIdx.x + c0;
    float Av[16];
    bool fast = true;
    #pragma unroll
    for (int s = 0; s < 16; ++s) {
        Av[s] = -__expf(alog[d * 16 + s]);
        fast = fast && (fabsf(Av[s] + (float)(s + 1)) < 1e-3f * (s + 1));
    }
    float h[16];
    size_t cbase = (((size_t)b * DI + d) * NC + c) * 16;
    #pragma unroll
    for (int q = 0; q < 4; ++q)
        *(float4*)&h[q*4] = *(const float4*)(cH + cbase + q*4);
    float Dd = Dp[d];
    int t0 = c * CLEN;
    if (fast) {
        for (int t = t0; t < t0 + CLEN; ++t) {
            size_t row = (size_t)b * LL + t;
            float dt = bf2f(dtb[row * 512 + d]);
            float x = bf2f(xi[row * 512 + d]);
            float dtx = dt * x;
            const float* bp = bc + row * 32;
            const float* cp = bc + row * 32 + 16;
            float e1 = __expf(-dt);
            float e2=e1*e1, e3=e2*e1, e4=e2*e2, e5=e3*e2, e6=e3*e3, e7=e4*e3, e8=e4*e4;
            float e9=e5*e4, e10=e5*e5, e11=e6*e5, e12=e6*e6, e13=e7*e6, e14=e7*e7, e15=e8*e7, e16=e8*e8;
            float pw[16] = {e1,e2,e3,e4,e5,e6,e7,e8,e9,e10,e11,e12,e13,e14,e15,e16};
            float y = 0.f;
            #pragma unroll
            for (int s = 0; s < 16; ++s) {
                h[s] = fmaf(pw[s], h[s], dtx * bp[s]);
                y = fmaf(h[s], cp[s], y);
            }
            float res = bf2f(xz[row * 1024 + 512 + d]);
            float g = (y + x * Dd) * (res / (1.f + __expf(-res)));
            xi[row * 512 + d] = f2bf(g);
        }
    } else {
        for (int t = t0; t < t0 + CLEN; ++t) {
            size_t row = (size_t)b * LL + t;
            float dt = bf2f(dtb[row * 512 + d]);
            float x = bf2f(xi[row * 512 + d]);
            float dtx = dt * x;
            const float* bp = bc + row * 32;
            const float* cp = bc + row * 32 + 16;
            float y = 0.f;
            #pragma unroll
            for (int s = 0; s < 16; ++s) {
                float dA = __expf(dt * Av[s]);
                h[s] = fmaf(dA, h[s], dtx * bp[s]);
                y = fmaf(h[s], cp[s], y);
            }
            float res = bf2f(xz[row * 1024 + 512 + d]);
            float g = (y + x * Dd) * (res / (1.f + __expf(-res)));
            xi[row * 512 + d] = f2bf(g);
        }
    }
}

// ---------------- last-row out_proj (layer 2) ------------------------------
__global__ __launch_bounds__(256) void out_proj_last_kernel(
    const ushort* __restrict__ xi, const float* __restrict__ W,
    float* __restrict__ h)
{
    int b = blockIdx.x, n = threadIdx.x;
    __shared__ float sy[DI];
    const ushort* yrow = xi + ((size_t)b * LL + (LL - 1)) * DI;
    for (int k = threadIdx.x; k < DI; k += 256) sy[k] = bf2f(yrow[k]);
    __syncthreads();
    const float* wr = W + (size_t)n * DI;
    float acc = 0.f;
    for (int k = 0; k < DI; k += 4) {
        float4 wv = *(const float4*)(wr + k);
        acc = fmaf(sy[k+0], wv.x, acc);
        acc = fmaf(sy[k+1], wv.y, acc);
        acc = fmaf(sy[k+2], wv.z, acc);
        acc = fmaf(sy[k+3], wv.w, acc);
    }
    h[((size_t)b * LL + (LL - 1)) * DM + n] += acc;
}

// ---------------- final LN (last row only) + head --------------------------
__global__ __launch_bounds__(256) void ln_head_kernel(
    const float* __restrict__ h, const float* __restrict__ lng,
    const float* __restrict__ lnb, const float* __restrict__ hw,
    const float* __restrict__ hb, float* __restrict__ out)
{
    int b = blockIdx.x, tid = threadIdx.x;
    __shared__ float sh[DM];
    __shared__ float r1[4], r2[4];
    float v = h[((size_t)b * LL + (LL - 1)) * DM + tid];
    float s = v;
    #pragma unroll
    for (int o = 32; o >= 1; o >>= 1) s += __shfl_down(s, o);
    if ((tid & 63) == 0) r1[tid >> 6] = s;
    __syncthreads();
    float mu = (r1[0] + r1[1] + r1[2] + r1[3]) * (1.f / 256.f);
    float dv = v - mu;
    float q = dv * dv;
    #pragma unroll
    for (int o = 32; o >= 1; o >>= 1) q += __shfl_down(q, o);
    if ((tid & 63) == 0) r2[tid >> 6] = q;
    __syncthreads();
    float var = (r2[0] + r2[1] + r2[2] + r2[3]) * (1.f / 256.f);
    sh[tid] = dv * rsqrtf(var + LN_EPS) * lng[tid] + lnb[tid];
    __syncthreads();
    if (tid < NOUTK) {
        const float* wr = hw + (size_t)tid * DM;
        float acc = hb[tid];
        for (int d2 = 0; d2 < DM; d2 += 4) {
            float4 wv = *(const float4*)(wr + d2);
            acc = fmaf(sh[d2+0], wv.x, acc);
            acc = fmaf(sh[d2+1], wv.y, acc);
            acc = fmaf(sh[d2+2], wv.z, acc);
            acc = fmaf(sh[d2+3], wv.w, acc);
        }
        out[b * NOUTK + tid] = acc;
    }
}

extern "C" void kernel_launch(void* const* d_in, const int* in_sizes, int n_in,
                              void* d_out, int out_size, void* d_ws, size_t ws_size,
                              hipStream_t stream)
{
    const float* x    = (const float*)d_in[0];
    const float* encw = (const float*)d_in[1];
    const float* encb = (const float*)d_in[2];
    const float* inw  = (const float*)d_in[3];
    const float* cw   = (const float*)d_in[4];
    const float* cb   = (const float*)d_in[5];
    const float* xpw  = (const float*)d_in[6];
    const float* dtw  = (const float*)d_in[7];
    const float* dtb  = (const float*)d_in[8];
    const float* alog = (const float*)d_in[9];
    const float* Dp   = (const float*)d_in[10];
    const float* opw  = (const float*)d_in[11];
    const float* lng  = (const float*)d_in[12];
    const float* lnb  = (const float*)d_in[13];
    const float* hw   = (const float*)d_in[14];
    const float* hb   = (const float*)d_in[15];
    float* out = (float*)d_out;

    float* ws   = (float*)d_ws;
    float* h    = ws;                               // BL*256 f32
    float* bc   = h   + (size_t)BL * DM;            // BL*32 f32 (B|C)
    float* cA   = bc  + (size_t)BL * 32;            // B*DI*NC*16 f32
    float* cH   = cA  + (size_t)BB * DI * NC * DS;
    ushort* h_bf    = (ushort*)(cH + (size_t)BB * DI * NC * DS);
    ushort* xz_bf   = h_bf  + (size_t)BL * DM;      // BL*1024
    ushort* xi_bf   = xz_bf + (size_t)BL * 1024;    // BL*512
    ushort* dt_bf   = xi_bf + (size_t)BL * DI;      // BL*512 (softplus'd dt)
    ushort* inw_bf  = dt_bf + (size_t)BL * DI;      // 2*1024*256
    ushort* opw_bf  = inw_bf + 2 * 1024 * DM;       // 2*256*512
    ushort* comb_bf = opw_bf + 2 * DM * DI;         // 2*640*512

    dim3 blk(256, 1, 1);

    cast_bf16_kernel<<<dim3((2*1024*DM)/256), blk, 0, stream>>>(inw, inw_bf, 2*1024*DM);
    cast_bf16_kernel<<<dim3((2*DM*DI)/256), blk, 0, stream>>>(opw, opw_bf, 2*DM*DI);
    build_comb_kernel<<<dim3((2*640*512)/256), blk, 0, stream>>>(xpw, dtw, comb_bf);

    enc_kernel<<<dim3(BL/4), blk, 0, stream>>>(x, encw, encb, h, h_bf);

    for (int l = 0; l < 2; ++l) {
        // in_proj -> xz_bf (bf16 only)
        mfma_gemm<0,false,false,true><<<dim3(1024/128, BL/64), blk, 0, stream>>>(
            h_bf, DM, inw_bf + (size_t)l * 1024 * DM, nullptr,
            nullptr, 0, xz_bf, 1024, DM);
        // conv + silu -> xi_bf
        conv_silu_kernel<<<dim3(BL * 128 / 256), blk, 0, stream>>>(
            xz_bf, cw + l * DI * 4, cb + l * DI, xi_bf);
        // combined xproj+dtproj: dt_bf = bf16(softplus(xi@Wdt^T + dtb)),
        // bc = f32 [B|C]
        mfma_gemm<1,false,false,false><<<dim3(LDB/128, BL/64), blk, 0, stream>>>(
            xi_bf, DI, comb_bf + (size_t)l * LDB * DI, dtb + l * DI,
            bc, 32, dt_bf, 512, DI);
        // scan
        scan_phase1<<<dim3(NC, BB, 2), blk, 0, stream>>>(
            xi_bf, dt_bf, bc, alog + (size_t)l * DI * 16, cA, cH);
        scan_phase2<<<dim3(BB * DI), blk, 0, stream>>>(cA, cH);
        if (l == 0) {
            scan_phase3<<<dim3(NC, BB, 2), blk, 0, stream>>>(
                xz_bf, xi_bf, dt_bf, bc, alog + (size_t)l * DI * 16,
                Dp + l * DI, cH, 0);
            mfma_gemm<0,true,true,true><<<dim3(DM/128, BL/64), blk, 0, stream>>>(
                xi_bf, DI, opw_bf + (size_t)l * DM * DI, nullptr,
                h, DM, h_bf, DM, DI);
        } else {
            scan_phase3<<<dim3(1, BB, 2), blk, 0, stream>>>(
                xz_bf, xi_bf, dt_bf, bc, alog + (size_t)l * DI * 16,
                Dp + l * DI, cH, NC - 1);
            out_proj_last_kernel<<<dim3(BB), blk, 0, stream>>>(
                xi_bf, opw + (size_t)l * DM * DI, h);
        }
    }

    ln_head_kernel<<<dim3(BB), blk, 0, stream>>>(h, lng, lnb, hw, hb, out);
}

// Round 5
// 345.868 us; speedup vs baseline: 1.0843x; 1.0690x over previous
//
#include <hip/hip_runtime.h>
#include <hip/hip_bf16.h>
#include <math.h>

#define BB 4
#define LL 4096
#define DM 256
#define DI 512
#define DS 16
#define NOUTK 128
#define LN_EPS 1e-5f
#define NC 128
#define CLEN (LL/NC)
#define BL (BB*LL)
#define LDB 640

typedef __attribute__((ext_vector_type(8))) short short8;
typedef __attribute__((ext_vector_type(4))) float f32x4;

__device__ __forceinline__ ushort f2bf(float f) {
    union { float f; unsigned u; } v; v.f = f;
    unsigned r = (v.u + 0x7FFF + ((v.u >> 16) & 1)) >> 16;
    return (ushort)r;
}
__device__ __forceinline__ float bf2f(ushort u) {
    union { unsigned u; float f; } v; v.u = ((unsigned)u) << 16;
    return v.f;
}

// ---------------- fused weight prep ----------------------------------------
// [0, n1): inw -> bf16;  [n1, n1+n2): opw -> bf16;  [n1+n2, +n3): comb build.
#define PREP_N1 (2*1024*256)
#define PREP_N2 (2*256*512)
#define PREP_N3 (2*640*512)
__global__ __launch_bounds__(256) void prep_kernel(
    const float* __restrict__ inw, const float* __restrict__ opw,
    const float* __restrict__ xpw, const float* __restrict__ dtw,
    ushort* __restrict__ inw_bf, ushort* __restrict__ opw_bf,
    ushort* __restrict__ comb_bf)
{
    int i = blockIdx.x * 256 + threadIdx.x;
    if (i < PREP_N1) {
        inw_bf[i] = f2bf(inw[i]);
        return;
    }
    int j = i - PREP_N1;
    if (j < PREP_N2) {
        opw_bf[j] = f2bf(opw[j]);
        return;
    }
    int m = j - PREP_N2;
    if (m >= PREP_N3) return;
    int l = m / (640 * 512);
    int rem = m - l * 640 * 512;
    int row = rem >> 9, k = rem & 511;
    const float* xp = xpw + l * 48 * 512;
    const float* dw = dtw + l * 512 * 16;
    float v;
    if (row < 512) {
        v = 0.f;
        #pragma unroll
        for (int r = 0; r < 16; ++r)
            v = fmaf(dw[row * 16 + r], xp[r * 512 + k], v);
    } else if (row < 544) {
        v = xp[(row - 512 + 16) * 512 + k];
    } else v = 0.f;
    comb_bf[m] = f2bf(v);
}

// ---------------- encoder --------------------------------------------------
__global__ __launch_bounds__(256) void enc_kernel(
    const float* __restrict__ x, const float* __restrict__ w,
    const float* __restrict__ b, float* __restrict__ h,
    ushort* __restrict__ hbf)
{
    __shared__ float sw[256 * 33];
    __shared__ float sx[4][32];
    int tid = threadIdx.x;
    for (int i = tid; i < 256 * 8; i += 256) {
        float4 v = ((const float4*)w)[i];
        int r = i >> 3, c = (i & 7) * 4;
        sw[r * 33 + c + 0] = v.x; sw[r * 33 + c + 1] = v.y;
        sw[r * 33 + c + 2] = v.z; sw[r * 33 + c + 3] = v.w;
    }
    int row0 = blockIdx.x * 4;
    if (tid < 32) {
        for (int rr = 0; rr < 4; ++rr)
            sx[rr][tid] = x[(size_t)(row0 + rr) * 32 + tid];
    }
    __syncthreads();
    float bb = b[tid];
    #pragma unroll
    for (int rr = 0; rr < 4; ++rr) {
        float acc = bb;
        #pragma unroll
        for (int k = 0; k < 32; ++k)
            acc = fmaf(sx[rr][k], sw[tid * 33 + k], acc);
        size_t o = (size_t)(row0 + rr) * DM + tid;
        h[o] = acc;
        hbf[o] = f2bf(acc);
    }
}

// ---------------- bf16 MFMA GEMM: C = epi(A @ W^T) -------------------------
// Tile 64(M) x 128(N), 4 waves of 32x64, single-buffered 24 KB LDS
// (m97-style 2-barrier k-loop; latency hidden by 6 co-resident blocks).
// NOTE (R3 post-mortem): do NOT double-buffer — 48 KB LDS halves residency
// and the lost TLP costs more than the explicit pipeline gains (+31 us).
// launch_bounds(256,6): force VGPR<=85 so LDS cap (6 blocks/CU) is reached.
// EPI: 0 none; 1 combined-xproj:
//        cols<512:   dt_bf[row*ldcbf+col]  = bf16(softplus(v + bias[col]))
//        512<=c<544: bc  [row*ldc + c-512] = v   (f32 B/C block)
template<int EPI, bool F32OUT, bool RESID, bool BF16OUT>
__global__ __launch_bounds__(256, 6) void mfma_gemm(
    const ushort* __restrict__ A, int lda,
    const ushort* __restrict__ W,
    const float* __restrict__ bias,
    float* __restrict__ C, int ldc,
    ushort* __restrict__ Cbf, int ldcbf,
    int K)
{
    __shared__ ushort As[64 * 64];
    __shared__ ushort Ws[128 * 64];
    const int tid = threadIdx.x;

    // XCD-aware bijective swizzle (nwg % 8 == 0 for all our launches)
    int nwg = gridDim.x * gridDim.y;
    int wlin = blockIdx.y * gridDim.x + blockIdx.x;
    int gx = blockIdx.x, gy = blockIdx.y;
    if ((nwg & 7) == 0) {
        int q = nwg >> 3;
        int s = (wlin & 7) * q + (wlin >> 3);
        gx = s % gridDim.x;
        gy = s / gridDim.x;
    }
    const int bm = gy * 64;
    const int bn = gx * 128;
    const int wid = tid >> 6, lane = tid & 63;
    const int wrow = (wid >> 1) * 32, wcol = (wid & 1) * 64;
    const int sr = tid >> 3;
    const int sc = tid & 7;

    f32x4 acc[2][4];
    #pragma unroll
    for (int mi = 0; mi < 2; ++mi)
        #pragma unroll
        for (int ni = 0; ni < 4; ++ni)
            acc[mi][ni] = (f32x4){0.f, 0.f, 0.f, 0.f};

    const int nk = K >> 6;          // 4 (K=256) or 8 (K=512)
    for (int t = 0; t < nk; ++t) {
        const int k0 = t << 6;
        #pragma unroll
        for (int it = 0; it < 2; ++it) {
            int r = it * 32 + sr;
            int csrc = sc ^ (r & 7);
            __builtin_amdgcn_global_load_lds(
                (const __attribute__((address_space(1))) unsigned int*)
                    (A + (size_t)(bm + r) * lda + k0 + csrc * 8),
                (__attribute__((address_space(3))) unsigned int*)
                    (As + r * 64 + sc * 8), 16, 0, 0);
        }
        #pragma unroll
        for (int it = 0; it < 4; ++it) {
            int r = it * 32 + sr;
            int csrc = sc ^ (r & 7);
            __builtin_amdgcn_global_load_lds(
                (const __attribute__((address_space(1))) unsigned int*)
                    (W + (size_t)(bn + r) * K + k0 + csrc * 8),
                (__attribute__((address_space(3))) unsigned int*)
                    (Ws + r * 64 + sc * 8), 16, 0, 0);
        }
        __syncthreads();
        #pragma unroll
        for (int kk = 0; kk < 2; ++kk) {
            short8 af[2], bfr[4];
            #pragma unroll
            for (int mi = 0; mi < 2; ++mi) {
                int r = wrow + mi * 16 + (lane & 15);
                int c = (lane >> 4) + kk * 4;
                af[mi] = *(const short8*)(As + r * 64 + ((c ^ (r & 7)) << 3));
            }
            #pragma unroll
            for (int ni = 0; ni < 4; ++ni) {
                int r = wcol + ni * 16 + (lane & 15);
                int c = (lane >> 4) + kk * 4;
                bfr[ni] = *(const short8*)(Ws + r * 64 + ((c ^ (r & 7)) << 3));
            }
            #pragma unroll
            for (int mi = 0; mi < 2; ++mi)
                #pragma unroll
                for (int ni = 0; ni < 4; ++ni)
                    acc[mi][ni] = __builtin_amdgcn_mfma_f32_16x16x32_bf16(
                        af[mi], bfr[ni], acc[mi][ni], 0, 0, 0);
        }
        __syncthreads();
    }

    #pragma unroll
    for (int mi = 0; mi < 2; ++mi)
        #pragma unroll
        for (int ni = 0; ni < 4; ++ni) {
            int col = bn + wcol + ni * 16 + (lane & 15);
            #pragma unroll
            for (int r = 0; r < 4; ++r) {
                int row = bm + wrow + mi * 16 + (lane >> 4) * 4 + r;
                float v = acc[mi][ni][r];
                if (EPI == 1) {
                    if (col < 512) {
                        float u = v + bias[col];
                        float sp = fmaxf(u, 0.f) + __logf(1.f + __expf(-fabsf(u)));
                        Cbf[(size_t)row * ldcbf + col] = f2bf(sp);
                    } else if (col < 544) {
                        C[(size_t)row * ldc + (col - 512)] = v;
                    }
                } else {
                    if (F32OUT) {
                        float* cp = C + (size_t)row * ldc + col;
                        float vv = v;
                        if (RESID) vv += *cp;
                        *cp = vv;
                        if (BF16OUT) Cbf[(size_t)row * ldcbf + col] = f2bf(vv);
                    } else if (BF16OUT) {
                        Cbf[(size_t)row * ldcbf + col] = f2bf(v);
                    }
                }
            }
        }
}

// ---------------- causal conv (width 4) + bias + silu, bf16 in/out ---------
__global__ __launch_bounds__(256) void conv_silu_kernel(
    const ushort* __restrict__ xz, const float* __restrict__ cw,
    const float* __restrict__ cb, ushort* __restrict__ xi)
{
    int idx = blockIdx.x * 256 + threadIdx.x;   // over BL*128
    int d4 = (idx & 127) * 4;
    int bt = idx >> 7;
    int t = bt & (LL - 1);
    const ushort* base = xz + (size_t)bt * 1024 + d4;
    float acc[4];
    float4 w[4];
    #pragma unroll
    for (int j = 0; j < 4; ++j) {
        acc[j] = cb[d4 + j];
        w[j] = *(const float4*)(cw + (d4 + j) * 4);
    }
    #pragma unroll
    for (int k = 0; k < 4; ++k) {
        int back = 3 - k;
        if (t >= back) {
            ushort4 v = *(const ushort4*)(base - back * 1024);
            float wk0 = (k==0)?w[0].x:(k==1)?w[0].y:(k==2)?w[0].z:w[0].w;
            float wk1 = (k==0)?w[1].x:(k==1)?w[1].y:(k==2)?w[1].z:w[1].w;
            float wk2 = (k==0)?w[2].x:(k==1)?w[2].y:(k==2)?w[2].z:w[2].w;
            float wk3 = (k==0)?w[3].x:(k==1)?w[3].y:(k==2)?w[3].z:w[3].w;
            acc[0] = fmaf(bf2f(v.x), wk0, acc[0]);
            acc[1] = fmaf(bf2f(v.y), wk1, acc[1]);
            acc[2] = fmaf(bf2f(v.z), wk2, acc[2]);
            acc[3] = fmaf(bf2f(v.w), wk3, acc[3]);
        }
    }
    ushort4 o;
    float s0 = acc[0] / (1.f + __expf(-acc[0]));
    float s1 = acc[1] / (1.f + __expf(-acc[1]));
    float s2 = acc[2] / (1.f + __expf(-acc[2]));
    float s3 = acc[3] / (1.f + __expf(-acc[3]));
    o.x = f2bf(s0); o.y = f2bf(s1); o.z = f2bf(s2); o.w = f2bf(s3);
    *(ushort4*)(xi + (size_t)bt * 512 + d4) = o;
}

// ---------------- chunked selective scan -----------------------------------
// dt (softplus applied) is bf16 at dtb[row*512 + d]; B/C are f32 at
// bc[row*32 + {0..15 | 16..31}].
// Chunk A-product is exp(Av[s] * sum(dt)) EXACTLY (even off the fast path),
// so phase1 stores only S = sum(dt) (1 float) per (b,d,c); phase2
// reconstructs the per-s decay factor from S and alog.
__global__ __launch_bounds__(256) void scan_phase1(
    const ushort* __restrict__ xi, const ushort* __restrict__ dtb,
    const float* __restrict__ bc,
    const float* __restrict__ alog,
    float* __restrict__ cS, float* __restrict__ cH)
{
    int d = blockIdx.z * 256 + threadIdx.x;
    int b = blockIdx.y, c = blockIdx.x;
    float Av[16];
    bool fast = true;
    #pragma unroll
    for (int s = 0; s < 16; ++s) {
        Av[s] = -__expf(alog[d * 16 + s]);
        fast = fast && (fabsf(Av[s] + (float)(s + 1)) < 1e-3f * (s + 1));
    }
    float h[16];
    #pragma unroll
    for (int s = 0; s < 16; ++s) h[s] = 0.f;
    float S = 0.f;
    int t0 = c * CLEN;
    if (fast) {
        for (int t = t0; t < t0 + CLEN; ++t) {
            size_t row = (size_t)b * LL + t;
            float dt = bf2f(dtb[row * 512 + d]);
            float x = bf2f(xi[row * 512 + d]);
            float dtx = dt * x;
            S += dt;
            const float* bp = bc + row * 32;
            float e1 = __expf(-dt);
            float e2=e1*e1, e3=e2*e1, e4=e2*e2, e5=e3*e2, e6=e3*e3, e7=e4*e3, e8=e4*e4;
            float e9=e5*e4, e10=e5*e5, e11=e6*e5, e12=e6*e6, e13=e7*e6, e14=e7*e7, e15=e8*e7, e16=e8*e8;
            float pw[16] = {e1,e2,e3,e4,e5,e6,e7,e8,e9,e10,e11,e12,e13,e14,e15,e16};
            #pragma unroll
            for (int s = 0; s < 16; ++s)
                h[s] = fmaf(pw[s], h[s], dtx * bp[s]);
        }
    } else {
        for (int t = t0; t < t0 + CLEN; ++t) {
            size_t row = (size_t)b * LL + t;
            float dt = bf2f(dtb[row * 512 + d]);
            float x = bf2f(xi[row * 512 + d]);
            float dtx = dt * x;
            S += dt;
            const float* bp = bc + row * 32;
            #pragma unroll
            for (int s = 0; s < 16; ++s) {
                float dA = __expf(dt * Av[s]);
                h[s] = fmaf(dA, h[s], dtx * bp[s]);
            }
        }
    }
    cS[((size_t)b * DI + d) * NC + c] = S;
    size_t base = (((size_t)b * DI + d) * NC + c) * 16;
    #pragma unroll
    for (int q = 0; q < 4; ++q)
        *(float4*)(cH + base + q*4) = *(float4*)&h[q*4];
}

// Parallel chunk-prefix: one block per (b,d); 16 threads per s-value,
// each composing 8 chunks; shfl-scan of affine maps F(x)=Ax+H across the
// 16-lane segment (serial chain 128 -> 8+4+8). Decay a = exp(Av[s]*S).
__global__ __launch_bounds__(256) void scan_phase2(
    const float* __restrict__ cS, float* __restrict__ cH,
    const float* __restrict__ alog)
{
    int bd = blockIdx.x;            // b*DI + d
    int d = bd & (DI - 1);
    int tid = threadIdx.x;
    int s = tid >> 4;               // 0..15
    int g = tid & 15;               // chunk group (8 chunks each)
    float Avs = -__expf(alog[d * 16 + s]);
    size_t sbase = (size_t)bd * NC;
    size_t base = (size_t)bd * NC * 16 + s;
    float a8[8], h8[8];
    #pragma unroll
    for (int j = 0; j < 8; ++j) {
        float Sj = cS[sbase + g * 8 + j];
        a8[j] = __expf(Avs * Sj);
        h8[j] = cH[base + (size_t)(g * 8 + j) * 16];
    }
    float A = 1.f, H = 0.f;
    #pragma unroll
    for (int j = 0; j < 8; ++j) {
        H = fmaf(a8[j], H, h8[j]);
        A *= a8[j];
    }
    #pragma unroll
    for (int off = 1; off < 16; off <<= 1) {
        float Ap = __shfl_up(A, off, 16);
        float Hp = __shfl_up(H, off, 16);
        if (g >= off) { H = fmaf(A, Hp, H); A *= Ap; }
    }
    float init = __shfl_up(H, 1, 16);
    if (g == 0) init = 0.f;
    #pragma unroll
    for (int j = 0; j < 8; ++j) {
        size_t o = base + (size_t)(g * 8 + j) * 16;
        cH[o] = init;
        init = fmaf(a8[j], init, h8[j]);
    }
}

__global__ __launch_bounds__(256) void scan_phase3(
    const ushort* __restrict__ xz,   // bf16, ld 1024; res at cols 512..1023
    ushort* __restrict__ xi,
    const ushort* __restrict__ dtb,
    const float* __restrict__ bc,
    const float* __restrict__ alog,
    const float* __restrict__ Dp,
    const float* __restrict__ cH,
    int c0)
{
    int d = blockIdx.z * 256 + threadIdx.x;
    int b = blockIdx.y;
    int c = blockIdx.x + c0;
    float Av[16];
    bool fast = true;
    #pragma unroll
    for (int s = 0; s < 16; ++s) {
        Av[s] = -__expf(alog[d * 16 + s]);
        fast = fast && (fabsf(Av[s] + (float)(s + 1)) < 1e-3f * (s + 1));
    }
    float h[16];
    size_t cbase = (((size_t)b * DI + d) * NC + c) * 16;
    #pragma unroll
    for (int q = 0; q < 4; ++q)
        *(float4*)&h[q*4] = *(const float4*)(cH + cbase + q*4);
    float Dd = Dp[d];
    int t0 = c * CLEN;
    if (fast) {
        for (int t = t0; t < t0 + CLEN; ++t) {
            size_t row = (size_t)b * LL + t;
            float dt = bf2f(dtb[row * 512 + d]);
            float x = bf2f(xi[row * 512 + d]);
            float dtx = dt * x;
            const float* bp = bc + row * 32;
            const float* cp = bc + row * 32 + 16;
            float e1 = __expf(-dt);
            float e2=e1*e1, e3=e2*e1, e4=e2*e2, e5=e3*e2, e6=e3*e3, e7=e4*e3, e8=e4*e4;
            float e9=e5*e4, e10=e5*e5, e11=e6*e5, e12=e6*e6, e13=e7*e6, e14=e7*e7, e15=e8*e7, e16=e8*e8;
            float pw[16] = {e1,e2,e3,e4,e5,e6,e7,e8,e9,e10,e11,e12,e13,e14,e15,e16};
            float y = 0.f;
            #pragma unroll
            for (int s = 0; s < 16; ++s) {
                h[s] = fmaf(pw[s], h[s], dtx * bp[s]);
                y = fmaf(h[s], cp[s], y);
            }
            float res = bf2f(xz[row * 1024 + 512 + d]);
            float g = (y + x * Dd) * (res / (1.f + __expf(-res)));
            xi[row * 512 + d] = f2bf(g);
        }
    } else {
        for (int t = t0; t < t0 + CLEN; ++t) {
            size_t row = (size_t)b * LL + t;
            float dt = bf2f(dtb[row * 512 + d]);
            float x = bf2f(xi[row * 512 + d]);
            float dtx = dt * x;
            const float* bp = bc + row * 32;
            const float* cp = bc + row * 32 + 16;
            float y = 0.f;
            #pragma unroll
            for (int s = 0; s < 16; ++s) {
                float dA = __expf(dt * Av[s]);
                h[s] = fmaf(dA, h[s], dtx * bp[s]);
                y = fmaf(h[s], cp[s], y);
            }
            float res = bf2f(xz[row * 1024 + 512 + d]);
            float g = (y + x * Dd) * (res / (1.f + __expf(-res)));
            xi[row * 512 + d] = f2bf(g);
        }
    }
}

// ---------------- last-row out_proj (layer 2) ------------------------------
__global__ __launch_bounds__(256) void out_proj_last_kernel(
    const ushort* __restrict__ xi, const float* __restrict__ W,
    float* __restrict__ h)
{
    int b = blockIdx.x, n = threadIdx.x;
    __shared__ float sy[DI];
    const ushort* yrow = xi + ((size_t)b * LL + (LL - 1)) * DI;
    for (int k = threadIdx.x; k < DI; k += 256) sy[k] = bf2f(yrow[k]);
    __syncthreads();
    const float* wr = W + (size_t)n * DI;
    float acc = 0.f;
    for (int k = 0; k < DI; k += 4) {
        float4 wv = *(const float4*)(wr + k);
        acc = fmaf(sy[k+0], wv.x, acc);
        acc = fmaf(sy[k+1], wv.y, acc);
        acc = fmaf(sy[k+2], wv.z, acc);
        acc = fmaf(sy[k+3], wv.w, acc);
    }
    h[((size_t)b * LL + (LL - 1)) * DM + n] += acc;
}

// ---------------- final LN (last row only) + head --------------------------
__global__ __launch_bounds__(256) void ln_head_kernel(
    const float* __restrict__ h, const float* __restrict__ lng,
    const float* __restrict__ lnb, const float* __restrict__ hw,
    const float* __restrict__ hb, float* __restrict__ out)
{
    int b = blockIdx.x, tid = threadIdx.x;
    __shared__ float sh[DM];
    __shared__ float r1[4], r2[4];
    float v = h[((size_t)b * LL + (LL - 1)) * DM + tid];
    float s = v;
    #pragma unroll
    for (int o = 32; o >= 1; o >>= 1) s += __shfl_down(s, o);
    if ((tid & 63) == 0) r1[tid >> 6] = s;
    __syncthreads();
    float mu = (r1[0] + r1[1] + r1[2] + r1[3]) * (1.f / 256.f);
    float dv = v - mu;
    float q = dv * dv;
    #pragma unroll
    for (int o = 32; o >= 1; o >>= 1) q += __shfl_down(q, o);
    if ((tid & 63) == 0) r2[tid >> 6] = q;
    __syncthreads();
    float var = (r2[0] + r2[1] + r2[2] + r2[3]) * (1.f / 256.f);
    sh[tid] = dv * rsqrtf(var + LN_EPS) * lng[tid] + lnb[tid];
    __syncthreads();
    if (tid < NOUTK) {
        const float* wr = hw + (size_t)tid * DM;
        float acc = hb[tid];
        for (int d2 = 0; d2 < DM; d2 += 4) {
            float4 wv = *(const float4*)(wr + d2);
            acc = fmaf(sh[d2+0], wv.x, acc);
            acc = fmaf(sh[d2+1], wv.y, acc);
            acc = fmaf(sh[d2+2], wv.z, acc);
            acc = fmaf(sh[d2+3], wv.w, acc);
        }
        out[b * NOUTK + tid] = acc;
    }
}

extern "C" void kernel_launch(void* const* d_in, const int* in_sizes, int n_in,
                              void* d_out, int out_size, void* d_ws, size_t ws_size,
                              hipStream_t stream)
{
    const float* x    = (const float*)d_in[0];
    const float* encw = (const float*)d_in[1];
    const float* encb = (const float*)d_in[2];
    const float* inw  = (const float*)d_in[3];
    const float* cw   = (const float*)d_in[4];
    const float* cb   = (const float*)d_in[5];
    const float* xpw  = (const float*)d_in[6];
    const float* dtw  = (const float*)d_in[7];
    const float* dtb  = (const float*)d_in[8];
    const float* alog = (const float*)d_in[9];
    const float* Dp   = (const float*)d_in[10];
    const float* opw  = (const float*)d_in[11];
    const float* lng  = (const float*)d_in[12];
    const float* lnb  = (const float*)d_in[13];
    const float* hw   = (const float*)d_in[14];
    const float* hb   = (const float*)d_in[15];
    float* out = (float*)d_out;

    float* ws   = (float*)d_ws;
    float* h    = ws;                               // BL*256 f32
    float* bc   = h   + (size_t)BL * DM;            // BL*32 f32 (B|C)
    float* cS   = bc  + (size_t)BL * 32;            // B*DI*NC f32 (sum dt)
    float* cH   = cS  + (size_t)BB * DI * NC;       // B*DI*NC*16 f32
    ushort* h_bf    = (ushort*)(cH + (size_t)BB * DI * NC * DS);
    ushort* xz_bf   = h_bf  + (size_t)BL * DM;      // BL*1024
    ushort* xi_bf   = xz_bf + (size_t)BL * 1024;    // BL*512
    ushort* dt_bf   = xi_bf + (size_t)BL * DI;      // BL*512 (softplus'd dt)
    ushort* inw_bf  = dt_bf + (size_t)BL * DI;      // 2*1024*256
    ushort* opw_bf  = inw_bf + 2 * 1024 * DM;       // 2*256*512
    ushort* comb_bf = opw_bf + 2 * DM * DI;         // 2*640*512

    dim3 blk(256, 1, 1);

    prep_kernel<<<dim3((PREP_N1 + PREP_N2 + PREP_N3) / 256), blk, 0, stream>>>(
        inw, opw, xpw, dtw, inw_bf, opw_bf, comb_bf);

    enc_kernel<<<dim3(BL/4), blk, 0, stream>>>(x, encw, encb, h, h_bf);

    for (int l = 0; l < 2; ++l) {
        // in_proj -> xz_bf (bf16 only)
        mfma_gemm<0,false,false,true><<<dim3(1024/128, BL/64), blk, 0, stream>>>(
            h_bf, DM, inw_bf + (size_t)l * 1024 * DM, nullptr,
            nullptr, 0, xz_bf, 1024, DM);
        // conv + silu -> xi_bf
        conv_silu_kernel<<<dim3(BL * 128 / 256), blk, 0, stream>>>(
            xz_bf, cw + l * DI * 4, cb + l * DI, xi_bf);
        // combined xproj+dtproj: dt_bf = bf16(softplus(xi@Wdt^T + dtb)),
        // bc = f32 [B|C]
        mfma_gemm<1,false,false,false><<<dim3(LDB/128, BL/64), blk, 0, stream>>>(
            xi_bf, DI, comb_bf + (size_t)l * LDB * DI, dtb + l * DI,
            bc, 32, dt_bf, 512, DI);
        // scan
        scan_phase1<<<dim3(NC, BB, 2), blk, 0, stream>>>(
            xi_bf, dt_bf, bc, alog + (size_t)l * DI * 16, cS, cH);
        scan_phase2<<<dim3(BB * DI), blk, 0, stream>>>(
            cS, cH, alog + (size_t)l * DI * 16);
        if (l == 0) {
            scan_phase3<<<dim3(NC, BB, 2), blk, 0, stream>>>(
                xz_bf, xi_bf, dt_bf, bc, alog + (size_t)l * DI * 16,
                Dp + l * DI, cH, 0);
            mfma_gemm<0,true,true,true><<<dim3(DM/128, BL/64), blk, 0, stream>>>(
                xi_bf, DI, opw_bf + (size_t)l * DM * DI, nullptr,
                h, DM, h_bf, DM, DI);
        } else {
            scan_phase3<<<dim3(1, BB, 2), blk, 0, stream>>>(
                xz_bf, xi_bf, dt_bf, bc, alog + (size_t)l * DI * 16,
                Dp + l * DI, cH, NC - 1);
            out_proj_last_kernel<<<dim3(BB), blk, 0, stream>>>(
                xi_bf, opw + (size_t)l * DM * DI, h);
        }
    }

    ln_head_kernel<<<dim3(BB), blk, 0, stream>>>(h, lng, lnb, hw, hb, out);
}

// Round 6
// 306.639 us; speedup vs baseline: 1.2231x; 1.1279x over previous
//
#include <hip/hip_runtime.h>
#include <hip/hip_bf16.h>
#include <math.h>

#define BB 4
#define LL 4096
#define DM 256
#define DI 512
#define DS 16
#define NOUTK 128
#define LN_EPS 1e-5f
#define NC 128
#define CLEN (LL/NC)
#define BL (BB*LL)
#define LDB 640

typedef __attribute__((ext_vector_type(8))) short short8;
typedef __attribute__((ext_vector_type(4))) float f32x4;

__device__ __forceinline__ ushort f2bf(float f) {
    union { float f; unsigned u; } v; v.f = f;
    unsigned r = (v.u + 0x7FFF + ((v.u >> 16) & 1)) >> 16;
    return (ushort)r;
}
__device__ __forceinline__ float bf2f(ushort u) {
    union { unsigned u; float f; } v; v.u = ((unsigned)u) << 16;
    return v.f;
}

// ---------------- fused weight prep ----------------------------------------
// [0, n1): inw -> bf16;  [n1, n1+n2): opw -> bf16;  [n1+n2, +n3): comb build.
#define PREP_N1 (2*1024*256)
#define PREP_N2 (2*256*512)
#define PREP_N3 (2*640*512)
__global__ __launch_bounds__(256) void prep_kernel(
    const float* __restrict__ inw, const float* __restrict__ opw,
    const float* __restrict__ xpw, const float* __restrict__ dtw,
    ushort* __restrict__ inw_bf, ushort* __restrict__ opw_bf,
    ushort* __restrict__ comb_bf)
{
    int i = blockIdx.x * 256 + threadIdx.x;
    if (i < PREP_N1) {
        inw_bf[i] = f2bf(inw[i]);
        return;
    }
    int j = i - PREP_N1;
    if (j < PREP_N2) {
        opw_bf[j] = f2bf(opw[j]);
        return;
    }
    int m = j - PREP_N2;
    if (m >= PREP_N3) return;
    int l = m / (640 * 512);
    int rem = m - l * 640 * 512;
    int row = rem >> 9, k = rem & 511;
    const float* xp = xpw + l * 48 * 512;
    const float* dw = dtw + l * 512 * 16;
    float v;
    if (row < 512) {
        v = 0.f;
        #pragma unroll
        for (int r = 0; r < 16; ++r)
            v = fmaf(dw[row * 16 + r], xp[r * 512 + k], v);
    } else if (row < 544) {
        v = xp[(row - 512 + 16) * 512 + k];
    } else v = 0.f;
    comb_bf[m] = f2bf(v);
}

// ---------------- encoder (bf16 residual stream only) ----------------------
__global__ __launch_bounds__(256) void enc_kernel(
    const float* __restrict__ x, const float* __restrict__ w,
    const float* __restrict__ b, ushort* __restrict__ hbf)
{
    __shared__ float sw[256 * 33];
    __shared__ float sx[4][32];
    int tid = threadIdx.x;
    for (int i = tid; i < 256 * 8; i += 256) {
        float4 v = ((const float4*)w)[i];
        int r = i >> 3, c = (i & 7) * 4;
        sw[r * 33 + c + 0] = v.x; sw[r * 33 + c + 1] = v.y;
        sw[r * 33 + c + 2] = v.z; sw[r * 33 + c + 3] = v.w;
    }
    int row0 = blockIdx.x * 4;
    if (tid < 32) {
        for (int rr = 0; rr < 4; ++rr)
            sx[rr][tid] = x[(size_t)(row0 + rr) * 32 + tid];
    }
    __syncthreads();
    float bb = b[tid];
    #pragma unroll
    for (int rr = 0; rr < 4; ++rr) {
        float acc = bb;
        #pragma unroll
        for (int k = 0; k < 32; ++k)
            acc = fmaf(sx[rr][k], sw[tid * 33 + k], acc);
        hbf[(size_t)(row0 + rr) * DM + tid] = f2bf(acc);
    }
}

// ---------------- bf16 MFMA GEMM: C = epi(A @ W^T) -------------------------
// Tile 64(M) x 128(N), 4 waves of 32x64, single-buffered 24 KB LDS
// (m97-style 2-barrier k-loop; latency hidden by co-resident blocks).
// NOTE (R3 post-mortem): do NOT double-buffer — 48 KB LDS halves residency
// and the lost TLP costs more than the explicit pipeline gains (+31 us).
// NOTE (R5 post-mortem): do NOT force launch_bounds(256,6) — VGPR cap <88
// suspected to spill in the k-loop (flat result despite -67MB traffic cuts).
// (256,4) is the proven config (R2: 344 us at fast clocks).
// EPI: 0 plain bf16 out; 1 combined-xproj (dt softplus->bf16, B/C->f32 bc);
//      2 residual bf16 read-modify-write on Cbf.
template<int EPI>
__global__ __launch_bounds__(256, 4) void mfma_gemm(
    const ushort* __restrict__ A, int lda,
    const ushort* __restrict__ W,
    const float* __restrict__ bias,
    float* __restrict__ C, int ldc,
    ushort* Cbf, int ldcbf,
    int K)
{
    __shared__ ushort As[64 * 64];
    __shared__ ushort Ws[128 * 64];
    const int tid = threadIdx.x;

    // XCD-aware bijective swizzle (nwg % 8 == 0 for all our launches)
    int nwg = gridDim.x * gridDim.y;
    int wlin = blockIdx.y * gridDim.x + blockIdx.x;
    int gx = blockIdx.x, gy = blockIdx.y;
    if ((nwg & 7) == 0) {
        int q = nwg >> 3;
        int s = (wlin & 7) * q + (wlin >> 3);
        gx = s % gridDim.x;
        gy = s / gridDim.x;
    }
    const int bm = gy * 64;
    const int bn = gx * 128;
    const int wid = tid >> 6, lane = tid & 63;
    const int wrow = (wid >> 1) * 32, wcol = (wid & 1) * 64;
    const int sr = tid >> 3;
    const int sc = tid & 7;

    f32x4 acc[2][4];
    #pragma unroll
    for (int mi = 0; mi < 2; ++mi)
        #pragma unroll
        for (int ni = 0; ni < 4; ++ni)
            acc[mi][ni] = (f32x4){0.f, 0.f, 0.f, 0.f};

    const int nk = K >> 6;          // 4 (K=256) or 8 (K=512)
    for (int t = 0; t < nk; ++t) {
        const int k0 = t << 6;
        #pragma unroll
        for (int it = 0; it < 2; ++it) {
            int r = it * 32 + sr;
            int csrc = sc ^ (r & 7);
            __builtin_amdgcn_global_load_lds(
                (const __attribute__((address_space(1))) unsigned int*)
                    (A + (size_t)(bm + r) * lda + k0 + csrc * 8),
                (__attribute__((address_space(3))) unsigned int*)
                    (As + r * 64 + sc * 8), 16, 0, 0);
        }
        #pragma unroll
        for (int it = 0; it < 4; ++it) {
            int r = it * 32 + sr;
            int csrc = sc ^ (r & 7);
            __builtin_amdgcn_global_load_lds(
                (const __attribute__((address_space(1))) unsigned int*)
                    (W + (size_t)(bn + r) * K + k0 + csrc * 8),
                (__attribute__((address_space(3))) unsigned int*)
                    (Ws + r * 64 + sc * 8), 16, 0, 0);
        }
        __syncthreads();
        #pragma unroll
        for (int kk = 0; kk < 2; ++kk) {
            short8 af[2], bfr[4];
            #pragma unroll
            for (int mi = 0; mi < 2; ++mi) {
                int r = wrow + mi * 16 + (lane & 15);
                int c = (lane >> 4) + kk * 4;
                af[mi] = *(const short8*)(As + r * 64 + ((c ^ (r & 7)) << 3));
            }
            #pragma unroll
            for (int ni = 0; ni < 4; ++ni) {
                int r = wcol + ni * 16 + (lane & 15);
                int c = (lane >> 4) + kk * 4;
                bfr[ni] = *(const short8*)(Ws + r * 64 + ((c ^ (r & 7)) << 3));
            }
            #pragma unroll
            for (int mi = 0; mi < 2; ++mi)
                #pragma unroll
                for (int ni = 0; ni < 4; ++ni)
                    acc[mi][ni] = __builtin_amdgcn_mfma_f32_16x16x32_bf16(
                        af[mi], bfr[ni], acc[mi][ni], 0, 0, 0);
        }
        __syncthreads();
    }

    #pragma unroll
    for (int mi = 0; mi < 2; ++mi)
        #pragma unroll
        for (int ni = 0; ni < 4; ++ni) {
            int col = bn + wcol + ni * 16 + (lane & 15);
            #pragma unroll
            for (int r = 0; r < 4; ++r) {
                int row = bm + wrow + mi * 16 + (lane >> 4) * 4 + r;
                float v = acc[mi][ni][r];
                if (EPI == 1) {
                    if (col < 512) {
                        float u = v + bias[col];
                        float sp = fmaxf(u, 0.f) + __logf(1.f + __expf(-fabsf(u)));
                        Cbf[(size_t)row * ldcbf + col] = f2bf(sp);
                    } else if (col < 544) {
                        C[(size_t)row * ldc + (col - 512)] = v;
                    }
                } else if (EPI == 2) {
                    size_t o = (size_t)row * ldcbf + col;
                    float vv = v + bf2f(Cbf[o]);
                    Cbf[o] = f2bf(vv);
                } else {
                    Cbf[(size_t)row * ldcbf + col] = f2bf(v);
                }
            }
        }
}

// ---------------- causal conv (width 4) + bias + silu, bf16 in/out ---------
// Register sliding window: each thread walks 8 consecutive timesteps for its
// 4 channels (read volume 11 rows per 8 outputs instead of 4 rows per 1).
__global__ __launch_bounds__(256) void conv_silu_kernel(
    const ushort* __restrict__ xz, const float* __restrict__ cw,
    const float* __restrict__ cb, ushort* __restrict__ xi)
{
    int idx = blockIdx.x * 256 + threadIdx.x;   // over (BL/8)*128
    int d4 = (idx & 127) * 4;
    int grp = idx >> 7;                          // 0 .. BL/8-1
    int b = grp >> 9;                            // LL/8 = 512 groups per b
    int t0 = (grp & 511) * 8;
    const ushort* base = xz + ((size_t)(b * LL + t0) * 1024) + d4;
    ushort* obase = xi + ((size_t)(b * LL + t0) * 512) + d4;

    float4 w0 = *(const float4*)(cw + (d4 + 0) * 4);
    float4 w1 = *(const float4*)(cw + (d4 + 1) * 4);
    float4 w2 = *(const float4*)(cw + (d4 + 2) * 4);
    float4 w3 = *(const float4*)(cw + (d4 + 3) * 4);
    float b0 = cb[d4 + 0], b1 = cb[d4 + 1], b2 = cb[d4 + 2], b3 = cb[d4 + 3];

    ushort4 z4 = {0, 0, 0, 0};
    ushort4 win0 = (t0 >= 3) ? *(const ushort4*)(base - 3 * 1024) : z4;
    ushort4 win1 = (t0 >= 2) ? *(const ushort4*)(base - 2 * 1024) : z4;
    ushort4 win2 = (t0 >= 1) ? *(const ushort4*)(base - 1 * 1024) : z4;

    #pragma unroll
    for (int k = 0; k < 8; ++k) {
        ushort4 cur = *(const ushort4*)(base + k * 1024);
        float a0 = b0, a1 = b1, a2 = b2, a3 = b3;
        a0 = fmaf(bf2f(win0.x), w0.x, a0); a1 = fmaf(bf2f(win0.y), w1.x, a1);
        a2 = fmaf(bf2f(win0.z), w2.x, a2); a3 = fmaf(bf2f(win0.w), w3.x, a3);
        a0 = fmaf(bf2f(win1.x), w0.y, a0); a1 = fmaf(bf2f(win1.y), w1.y, a1);
        a2 = fmaf(bf2f(win1.z), w2.y, a2); a3 = fmaf(bf2f(win1.w), w3.y, a3);
        a0 = fmaf(bf2f(win2.x), w0.z, a0); a1 = fmaf(bf2f(win2.y), w1.z, a1);
        a2 = fmaf(bf2f(win2.z), w2.z, a2); a3 = fmaf(bf2f(win2.w), w3.z, a3);
        a0 = fmaf(bf2f(cur.x),  w0.w, a0); a1 = fmaf(bf2f(cur.y),  w1.w, a1);
        a2 = fmaf(bf2f(cur.z),  w2.w, a2); a3 = fmaf(bf2f(cur.w),  w3.w, a3);
        ushort4 o;
        o.x = f2bf(a0 / (1.f + __expf(-a0)));
        o.y = f2bf(a1 / (1.f + __expf(-a1)));
        o.z = f2bf(a2 / (1.f + __expf(-a2)));
        o.w = f2bf(a3 / (1.f + __expf(-a3)));
        *(ushort4*)(obase + k * 512) = o;
        win0 = win1; win1 = win2; win2 = cur;
    }
}

// ---------------- chunked selective scan -----------------------------------
// dt (softplus applied) is bf16 at dtb[row*512 + d]; B/C are f32 at
// bc[row*32 + {0..15 | 16..31}].
// Chunk A-product is exp(Av[s] * sum(dt)) EXACTLY, so phase1 stores only
// S = sum(dt) per (b,d,c); phase2 reconstructs the decay from S and alog.
__global__ __launch_bounds__(256) void scan_phase1(
    const ushort* __restrict__ xi, const ushort* __restrict__ dtb,
    const float* __restrict__ bc,
    const float* __restrict__ alog,
    float* __restrict__ cS, float* __restrict__ cH)
{
    int d = blockIdx.z * 256 + threadIdx.x;
    int b = blockIdx.y, c = blockIdx.x;
    float Av[16];
    bool fast = true;
    #pragma unroll
    for (int s = 0; s < 16; ++s) {
        Av[s] = -__expf(alog[d * 16 + s]);
        fast = fast && (fabsf(Av[s] + (float)(s + 1)) < 1e-3f * (s + 1));
    }
    float h[16];
    #pragma unroll
    for (int s = 0; s < 16; ++s) h[s] = 0.f;
    float S = 0.f;
    int t0 = c * CLEN;
    if (fast) {
        for (int t = t0; t < t0 + CLEN; ++t) {
            size_t row = (size_t)b * LL + t;
            float dt = bf2f(dtb[row * 512 + d]);
            float x = bf2f(xi[row * 512 + d]);
            float dtx = dt * x;
            S += dt;
            const float* bp = bc + row * 32;
            float e1 = __expf(-dt);
            float e2=e1*e1, e3=e2*e1, e4=e2*e2, e5=e3*e2, e6=e3*e3, e7=e4*e3, e8=e4*e4;
            float e9=e5*e4, e10=e5*e5, e11=e6*e5, e12=e6*e6, e13=e7*e6, e14=e7*e7, e15=e8*e7, e16=e8*e8;
            float pw[16] = {e1,e2,e3,e4,e5,e6,e7,e8,e9,e10,e11,e12,e13,e14,e15,e16};
            #pragma unroll
            for (int s = 0; s < 16; ++s)
                h[s] = fmaf(pw[s], h[s], dtx * bp[s]);
        }
    } else {
        for (int t = t0; t < t0 + CLEN; ++t) {
            size_t row = (size_t)b * LL + t;
            float dt = bf2f(dtb[row * 512 + d]);
            float x = bf2f(xi[row * 512 + d]);
            float dtx = dt * x;
            S += dt;
            const float* bp = bc + row * 32;
            #pragma unroll
            for (int s = 0; s < 16; ++s) {
                float dA = __expf(dt * Av[s]);
                h[s] = fmaf(dA, h[s], dtx * bp[s]);
            }
        }
    }
    cS[((size_t)b * DI + d) * NC + c] = S;
    size_t base = (((size_t)b * DI + d) * NC + c) * 16;
    #pragma unroll
    for (int q = 0; q < 4; ++q)
        *(float4*)(cH + base + q*4) = *(float4*)&h[q*4];
}

// Parallel chunk-prefix: one block per (b,d); 16 threads per s-value,
// each composing 8 chunks; shfl-scan of affine maps F(x)=Ax+H across the
// 16-lane segment (serial chain 128 -> 8+4+8). Decay a = exp(Av[s]*S).
__global__ __launch_bounds__(256) void scan_phase2(
    const float* __restrict__ cS, float* __restrict__ cH,
    const float* __restrict__ alog)
{
    int bd = blockIdx.x;            // b*DI + d
    int d = bd & (DI - 1);
    int tid = threadIdx.x;
    int s = tid >> 4;               // 0..15
    int g = tid & 15;               // chunk group (8 chunks each)
    float Avs = -__expf(alog[d * 16 + s]);
    size_t sbase = (size_t)bd * NC;
    size_t base = (size_t)bd * NC * 16 + s;
    float a8[8], h8[8];
    #pragma unroll
    for (int j = 0; j < 8; ++j) {
        float Sj = cS[sbase + g * 8 + j];
        a8[j] = __expf(Avs * Sj);
        h8[j] = cH[base + (size_t)(g * 8 + j) * 16];
    }
    float A = 1.f, H = 0.f;
    #pragma unroll
    for (int j = 0; j < 8; ++j) {
        H = fmaf(a8[j], H, h8[j]);
        A *= a8[j];
    }
    #pragma unroll
    for (int off = 1; off < 16; off <<= 1) {
        float Ap = __shfl_up(A, off, 16);
        float Hp = __shfl_up(H, off, 16);
        if (g >= off) { H = fmaf(A, Hp, H); A *= Ap; }
    }
    float init = __shfl_up(H, 1, 16);
    if (g == 0) init = 0.f;
    #pragma unroll
    for (int j = 0; j < 8; ++j) {
        size_t o = base + (size_t)(g * 8 + j) * 16;
        cH[o] = init;
        init = fmaf(a8[j], init, h8[j]);
    }
}

__global__ __launch_bounds__(256) void scan_phase3(
    const ushort* __restrict__ xz,   // bf16, ld 1024; res at cols 512..1023
    ushort* __restrict__ xi,
    const ushort* __restrict__ dtb,
    const float* __restrict__ bc,
    const float* __restrict__ alog,
    const float* __restrict__ Dp,
    const float* __restrict__ cH,
    int c0)
{
    int d = blockIdx.z * 256 + threadIdx.x;
    int b = blockIdx.y;
    int c = blockIdx.x + c0;
    float Av[16];
    bool fast = true;
    #pragma unroll
    for (int s = 0; s < 16; ++s) {
        Av[s] = -__expf(alog[d * 16 + s]);
        fast = fast && (fabsf(Av[s] + (float)(s + 1)) < 1e-3f * (s + 1));
    }
    float h[16];
    size_t cbase = (((size_t)b * DI + d) * NC + c) * 16;
    #pragma unroll
    for (int q = 0; q < 4; ++q)
        *(float4*)&h[q*4] = *(const float4*)(cH + cbase + q*4);
    float Dd = Dp[d];
    int t0 = c * CLEN;
    if (fast) {
        for (int t = t0; t < t0 + CLEN; ++t) {
            size_t row = (size_t)b * LL + t;
            float dt = bf2f(dtb[row * 512 + d]);
            float x = bf2f(xi[row * 512 + d]);
            float dtx = dt * x;
            const float* bp = bc + row * 32;
            const float* cp = bc + row * 32 + 16;
            float e1 = __expf(-dt);
            float e2=e1*e1, e3=e2*e1, e4=e2*e2, e5=e3*e2, e6=e3*e3, e7=e4*e3, e8=e4*e4;
            float e9=e5*e4, e10=e5*e5, e11=e6*e5, e12=e6*e6, e13=e7*e6, e14=e7*e7, e15=e8*e7, e16=e8*e8;
            float pw[16] = {e1,e2,e3,e4,e5,e6,e7,e8,e9,e10,e11,e12,e13,e14,e15,e16};
            float y = 0.f;
            #pragma unroll
            for (int s = 0; s < 16; ++s) {
                h[s] = fmaf(pw[s], h[s], dtx * bp[s]);
                y = fmaf(h[s], cp[s], y);
            }
            float res = bf2f(xz[row * 1024 + 512 + d]);
            float g = (y + x * Dd) * (res / (1.f + __expf(-res)));
            xi[row * 512 + d] = f2bf(g);
        }
    } else {
        for (int t = t0; t < t0 + CLEN; ++t) {
            size_t row = (size_t)b * LL + t;
            float dt = bf2f(dtb[row * 512 + d]);
            float x = bf2f(xi[row * 512 + d]);
            float dtx = dt * x;
            const float* bp = bc + row * 32;
            const float* cp = bc + row * 32 + 16;
            float y = 0.f;
            #pragma unroll
            for (int s = 0; s < 16; ++s) {
                float dA = __expf(dt * Av[s]);
                h[s] = fmaf(dA, h[s], dtx * bp[s]);
                y = fmaf(h[s], cp[s], y);
            }
            float res = bf2f(xz[row * 1024 + 512 + d]);
            float g = (y + x * Dd) * (res / (1.f + __expf(-res)));
            xi[row * 512 + d] = f2bf(g);
        }
    }
}

// ---------------- last-row out_proj (layer 2) ------------------------------
// hlast[b][n] = bf16_resid(h_bf last row) + out_proj(y last row)
__global__ __launch_bounds__(256) void out_proj_last_kernel(
    const ushort* __restrict__ xi, const float* __restrict__ W,
    const ushort* __restrict__ hbf, float* __restrict__ hlast)
{
    int b = blockIdx.x, n = threadIdx.x;
    __shared__ float sy[DI];
    const ushort* yrow = xi + ((size_t)b * LL + (LL - 1)) * DI;
    for (int k = threadIdx.x; k < DI; k += 256) sy[k] = bf2f(yrow[k]);
    __syncthreads();
    const float* wr = W + (size_t)n * DI;
    float acc = 0.f;
    for (int k = 0; k < DI; k += 4) {
        float4 wv = *(const float4*)(wr + k);
        acc = fmaf(sy[k+0], wv.x, acc);
        acc = fmaf(sy[k+1], wv.y, acc);
        acc = fmaf(sy[k+2], wv.z, acc);
        acc = fmaf(sy[k+3], wv.w, acc);
    }
    hlast[b * DM + n] = acc + bf2f(hbf[((size_t)b * LL + (LL - 1)) * DM + n]);
}

// ---------------- final LN (last row only) + head --------------------------
__global__ __launch_bounds__(256) void ln_head_kernel(
    const float* __restrict__ hlast, const float* __restrict__ lng,
    const float* __restrict__ lnb, const float* __restrict__ hw,
    const float* __restrict__ hb, float* __restrict__ out)
{
    int b = blockIdx.x, tid = threadIdx.x;
    __shared__ float sh[DM];
    __shared__ float r1[4], r2[4];
    float v = hlast[b * DM + tid];
    float s = v;
    #pragma unroll
    for (int o = 32; o >= 1; o >>= 1) s += __shfl_down(s, o);
    if ((tid & 63) == 0) r1[tid >> 6] = s;
    __syncthreads();
    float mu = (r1[0] + r1[1] + r1[2] + r1[3]) * (1.f / 256.f);
    float dv = v - mu;
    float q = dv * dv;
    #pragma unroll
    for (int o = 32; o >= 1; o >>= 1) q += __shfl_down(q, o);
    if ((tid & 63) == 0) r2[tid >> 6] = q;
    __syncthreads();
    float var = (r2[0] + r2[1] + r2[2] + r2[3]) * (1.f / 256.f);
    sh[tid] = dv * rsqrtf(var + LN_EPS) * lng[tid] + lnb[tid];
    __syncthreads();
    if (tid < NOUTK) {
        const float* wr = hw + (size_t)tid * DM;
        float acc = hb[tid];
        for (int d2 = 0; d2 < DM; d2 += 4) {
            float4 wv = *(const float4*)(wr + d2);
            acc = fmaf(sh[d2+0], wv.x, acc);
            acc = fmaf(sh[d2+1], wv.y, acc);
            acc = fmaf(sh[d2+2], wv.z, acc);
            acc = fmaf(sh[d2+3], wv.w, acc);
        }
        out[b * NOUTK + tid] = acc;
    }
}

extern "C" void kernel_launch(void* const* d_in, const int* in_sizes, int n_in,
                              void* d_out, int out_size, void* d_ws, size_t ws_size,
                              hipStream_t stream)
{
    const float* x    = (const float*)d_in[0];
    const float* encw = (const float*)d_in[1];
    const float* encb = (const float*)d_in[2];
    const float* inw  = (const float*)d_in[3];
    const float* cw   = (const float*)d_in[4];
    const float* cb   = (const float*)d_in[5];
    const float* xpw  = (const float*)d_in[6];
    const float* dtw  = (const float*)d_in[7];
    const float* dtb  = (const float*)d_in[8];
    const float* alog = (const float*)d_in[9];
    const float* Dp   = (const float*)d_in[10];
    const float* opw  = (const float*)d_in[11];
    const float* lng  = (const float*)d_in[12];
    const float* lnb  = (const float*)d_in[13];
    const float* hw   = (const float*)d_in[14];
    const float* hb   = (const float*)d_in[15];
    float* out = (float*)d_out;

    float* ws   = (float*)d_ws;
    float* bc   = ws;                               // BL*32 f32 (B|C)
    float* cS   = bc  + (size_t)BL * 32;            // B*DI*NC f32 (sum dt)
    float* cH   = cS  + (size_t)BB * DI * NC;       // B*DI*NC*16 f32
    float* hlast = cH + (size_t)BB * DI * NC * DS;  // BB*DM f32
    ushort* h_bf    = (ushort*)(hlast + BB * DM);   // BL*256 (residual stream)
    ushort* xz_bf   = h_bf  + (size_t)BL * DM;      // BL*1024
    ushort* xi_bf   = xz_bf + (size_t)BL * 1024;    // BL*512
    ushort* dt_bf   = xi_bf + (size_t)BL * DI;      // BL*512 (softplus'd dt)
    ushort* inw_bf  = dt_bf + (size_t)BL * DI;      // 2*1024*256
    ushort* opw_bf  = inw_bf + 2 * 1024 * DM;       // 2*256*512
    ushort* comb_bf = opw_bf + 2 * DM * DI;         // 2*640*512

    dim3 blk(256, 1, 1);

    prep_kernel<<<dim3((PREP_N1 + PREP_N2 + PREP_N3) / 256), blk, 0, stream>>>(
        inw, opw, xpw, dtw, inw_bf, opw_bf, comb_bf);

    enc_kernel<<<dim3(BL/4), blk, 0, stream>>>(x, encw, encb, h_bf);

    for (int l = 0; l < 2; ++l) {
        // in_proj -> xz_bf (bf16 only)
        mfma_gemm<0><<<dim3(1024/128, BL/64), blk, 0, stream>>>(
            h_bf, DM, inw_bf + (size_t)l * 1024 * DM, nullptr,
            nullptr, 0, xz_bf, 1024, DM);
        // conv + silu -> xi_bf
        conv_silu_kernel<<<dim3(BL * 128 / 8 / 256), blk, 0, stream>>>(
            xz_bf, cw + l * DI * 4, cb + l * DI, xi_bf);
        // combined xproj+dtproj: dt_bf = bf16(softplus(xi@Wdt^T + dtb)),
        // bc = f32 [B|C]
        mfma_gemm<1><<<dim3(LDB/128, BL/64), blk, 0, stream>>>(
            xi_bf, DI, comb_bf + (size_t)l * LDB * DI, dtb + l * DI,
            bc, 32, dt_bf, 512, DI);
        // scan
        scan_phase1<<<dim3(NC, BB, 2), blk, 0, stream>>>(
            xi_bf, dt_bf, bc, alog + (size_t)l * DI * 16, cS, cH);
        scan_phase2<<<dim3(BB * DI), blk, 0, stream>>>(
            cS, cH, alog + (size_t)l * DI * 16);
        if (l == 0) {
            scan_phase3<<<dim3(NC, BB, 2), blk, 0, stream>>>(
                xz_bf, xi_bf, dt_bf, bc, alog + (size_t)l * DI * 16,
                Dp + l * DI, cH, 0);
            // out_proj with bf16 residual read-modify-write on h_bf
            mfma_gemm<2><<<dim3(DM/128, BL/64), blk, 0, stream>>>(
                xi_bf, DI, opw_bf + (size_t)l * DM * DI, nullptr,
                nullptr, 0, h_bf, DM, DI);
        } else {
            scan_phase3<<<dim3(1, BB, 2), blk, 0, stream>>>(
                xz_bf, xi_bf, dt_bf, bc, alog + (size_t)l * DI * 16,
                Dp + l * DI, cH, NC - 1);
            out_proj_last_kernel<<<dim3(BB), blk, 0, stream>>>(
                xi_bf, opw + (size_t)l * DM * DI, h_bf, hlast);
        }
    }

    ln_head_kernel<<<dim3(BB), blk, 0, stream>>>(hlast, lng, lnb, hw, hb, out);
}